// Round 5
// baseline (379.640 us; speedup 1.0000x reference)
//
#include <hip/hip_runtime.h>

// ---------------------------------------------------------------------------
// N=400000, E=2000000, B=8, C_IN=4, N_EDGE_TYPE=5, N_NODE_TYPE=7, C_OUT=32.
//
// HW model (measured, rounds 0-4):
//  - Global atomics into 88MB fp32 thrash L2: 504us (R1). DEAD END.
//  - Scatter write-merge RULE: rec region >= ~8 recs (64B), else
//    write-allocate amplification (R3: 141MB writes for 40MB payload).
//  - consume is x[col]-gather latency-bound; needs WAVES not LDS: R2
//    (36KB LDS, 37% occ) = 105us; R4 (143KB LDS, 17% occ, 3 phases) = 155us.
//  - Coarse regions (~80KB) are L2-resident -> window re-reads are cheap if
//    siblings share an XCD.
//  => R5: coarse sort (CW=2048, CH=4096, regions ~21 recs) + consume as one
//     256-thr/36KB block per (bucket,window): scan region from L2, filter
//     1/16, gather+accumulate+mix. Siblings pinned to one XCD by block-id
//     decode. 7 dispatches, no overflow path needed.
// ---------------------------------------------------------------------------

#define CH      4096       // edges per chunk
#define CW      2048       // coarse bucket width (nodes)
#define CWSH    11         // log2(CW)
#define WSZ     128        // consume window (nodes)
#define NW      16         // windows per bucket = CW/WSZ
#define NWSH    4          // log2(NW)
#define NBCMAX  512        // max coarse buckets (N <= 1M)

// ---- temb fused: per-batch block computes emb->h1->h2->inj ----------------
__global__ __launch_bounds__(256) void temb_fused_kernel(
    const float* __restrict__ t,
    const float* __restrict__ W1, const float* __restrict__ b1,
    const float* __restrict__ W2, const float* __restrict__ b2,
    const float* __restrict__ Wt, float* __restrict__ inj)
{
    int b = blockIdx.x;
    int tid = threadIdx.x;
    __shared__ float emb[128];
    __shared__ float s1[512];
    __shared__ float s2[512];
    __shared__ float red[256];
    float tv = t[b];
    if (tid < 128) {
        const float kStep = 9.210340371976184f / 63.0f;
        int k = tid & 63;
        float ang = tv * expf(-(float)k * kStep);
        emb[tid] = (tid < 64) ? sinf(ang) : cosf(ang);
    }
    __syncthreads();
    {
        float a0 = 0.f, a1 = 0.f;
        for (int k = 0; k < 128; ++k) {
            float e = emb[k];
            a0 += e * W1[k * 512 + tid];
            a1 += e * W1[k * 512 + tid + 256];
        }
        float v0 = a0 + b1[tid], v1 = a1 + b1[tid + 256];
        s1[tid]       = v0 / (1.0f + expf(-v0));
        s1[tid + 256] = v1 / (1.0f + expf(-v1));
    }
    __syncthreads();
    {
        float a0 = 0.f, a1 = 0.f;
        for (int k = 0; k < 512; ++k) {
            float e = s1[k];
            a0 += e * W2[k * 512 + tid];
            a1 += e * W2[k * 512 + tid + 256];
        }
        float v0 = a0 + b2[tid], v1 = a1 + b2[tid + 256];
        s2[tid]       = v0 / (1.0f + expf(-v0));
        s2[tid + 256] = v1 / (1.0f + expf(-v1));
    }
    __syncthreads();
    {
        int c = tid & 31, seg = tid >> 5;
        float acc = 0.f;
        int k0 = seg * 64;
        for (int k = k0; k < k0 + 64; ++k)
            acc += s2[k] * Wt[k * 32 + c];
        red[tid] = acc;
        __syncthreads();
        if (tid < 32) {
            float s = 0.f;
#pragma unroll
            for (int g = 0; g < 8; ++g) s += red[g * 32 + tid];
            inj[b * 32 + tid] = s;
        }
    }
}

// ---- legacy temb kernels (fallback path only) -----------------------------
__global__ __launch_bounds__(64) void temb1_kernel(
    const float* __restrict__ t, const float* __restrict__ W1,
    float* __restrict__ h1acc)
{
    int jb = blockIdx.x & 7, ks = blockIdx.x >> 3;
    __shared__ float embs[8][32];
    int tid = threadIdx.x;
    const float kStep = 9.210340371976184f / 63.0f;
    for (int i = tid; i < 256; i += 64) {
        int b = i >> 5, kk = i & 31;
        int k = ks * 32 + kk;
        float v;
        if (k < 64) v = sinf(t[b] * expf(-(float)k * kStep));
        else        v = cosf(t[b] * expf(-(float)(k - 64) * kStep));
        embs[b][kk] = v;
    }
    __syncthreads();
    int j = jb * 64 + tid;
    float acc[8] = {};
    for (int kk = 0; kk < 32; ++kk) {
        float w = W1[(ks * 32 + kk) * 512 + j];
#pragma unroll
        for (int b = 0; b < 8; ++b) acc[b] += embs[b][kk] * w;
    }
#pragma unroll
    for (int b = 0; b < 8; ++b) atomicAdd(&h1acc[b * 512 + j], acc[b]);
}

__global__ __launch_bounds__(64) void temb2_kernel(
    const float* __restrict__ h1acc, const float* __restrict__ b1,
    const float* __restrict__ W2, float* __restrict__ h2acc)
{
    int jb = blockIdx.x & 7, ks = blockIdx.x >> 3;
    __shared__ float h1s[8][64];
    int tid = threadIdx.x;
    for (int i = tid; i < 512; i += 64) {
        int b = i >> 6, kk = i & 63;
        int k = ks * 64 + kk;
        float v = h1acc[b * 512 + k] + b1[k];
        h1s[b][kk] = v / (1.0f + expf(-v));
    }
    __syncthreads();
    int j = jb * 64 + tid;
    float acc[8] = {};
    for (int kk = 0; kk < 64; ++kk) {
        float w = W2[(ks * 64 + kk) * 512 + j];
#pragma unroll
        for (int b = 0; b < 8; ++b) acc[b] += h1s[b][kk] * w;
    }
#pragma unroll
    for (int b = 0; b < 8; ++b) atomicAdd(&h2acc[b * 512 + j], acc[b]);
}

__global__ __launch_bounds__(256) void temb3_kernel(
    const float* __restrict__ h2acc, const float* __restrict__ b2,
    const float* __restrict__ Wt, float* __restrict__ inj)
{
    int ks = blockIdx.x;
    __shared__ float sws[8][64];
    int tid = threadIdx.x;
    for (int i = tid; i < 512; i += 256) {
        int b = i >> 6, kk = i & 63;
        int k = ks * 64 + kk;
        float v = h2acc[b * 512 + k] + b2[k];
        sws[b][kk] = v / (1.0f + expf(-v));
    }
    __syncthreads();
    int b = tid >> 5, c = tid & 31;
    float acc = 0.f;
    for (int kk = 0; kk < 64; ++kk)
        acc += sws[b][kk] * Wt[(ks * 64 + kk) * 32 + c];
    atomicAdd(&inj[tid], acc);
}

// ---- hist: block per chunk (grid NCHP); coarse LDS histogram --------------
// counts layout: counts[c * NBC + b]
__global__ __launch_bounds__(256) void hist_kernel(
    const int* __restrict__ ei, int* __restrict__ counts, int E, int NBC)
{
    __shared__ int h[NBCMAX];
    int tid = threadIdx.x;
    int c = blockIdx.x;
    for (int i = tid; i < NBC; i += 256) h[i] = 0;
    __syncthreads();
    int s = c * CH, e = min(s + CH, E);
    for (int i = s + tid; i < e; i += 256)
        atomicAdd(&h[ei[i] >> CWSH], 1);
    __syncthreads();
    int* row = counts + (size_t)c * NBC;
    for (int i = tid; i < NBC; i += 256) row[i] = h[i];
}

// ---- scanA: per-block sums over j = (b<<LOGC)+c order ---------------------
__global__ __launch_bounds__(256) void scanA_kernel(
    const int* __restrict__ counts, int* __restrict__ bsums,
    int M, int NBC, int LOGC)
{
    __shared__ int s[256];
    int tid = threadIdx.x;
    int j0 = blockIdx.x * 4096 + tid * 16;
    int maskC = (1 << LOGC) - 1;
    int p = 0;
#pragma unroll
    for (int k = 0; k < 16; ++k) {
        int j = j0 + k;
        if (j < M) {
            int b = j >> LOGC, c = j & maskC;
            p += counts[(size_t)c * NBC + b];
        }
    }
    s[tid] = p; __syncthreads();
    for (int off = 128; off > 0; off >>= 1) {
        if (tid < off) s[tid] += s[tid + off];
        __syncthreads();
    }
    if (tid == 0) bsums[blockIdx.x] = s[0];
}

// ---- scanB: exclusive scan of block sums (single block, <=1024) -----------
__global__ __launch_bounds__(1024) void scanB_kernel(
    int* __restrict__ bsums, int* __restrict__ bstart, int nblk, int NBC, int E)
{
    __shared__ int s[1024];
    int tid = threadIdx.x;
    int v = (tid < nblk) ? bsums[tid] : 0;
    s[tid] = v; __syncthreads();
    for (int off = 1; off < 1024; off <<= 1) {
        int u = (tid >= off) ? s[tid - off] : 0;
        __syncthreads();
        s[tid] += u;
        __syncthreads();
    }
    if (tid < nblk) bsums[tid] = s[tid] - v;          // exclusive
    if (tid == 0) bstart[NBC] = E;
}

// ---- scanC: exact base for every (bucket, chunk) region + bstart ----------
// base layout: base[(b<<LOGC)+c] (linear in scan order)
__global__ __launch_bounds__(256) void scanC_kernel(
    const int* __restrict__ counts, const int* __restrict__ bsums,
    int* __restrict__ base, int* __restrict__ bstart,
    int M, int NBC, int LOGC)
{
    __shared__ int s[256];
    int tid = threadIdx.x;
    int j0 = blockIdx.x * 4096 + tid * 16;
    int maskC = (1 << LOGC) - 1;
    int v[16]; int p = 0;
#pragma unroll
    for (int k = 0; k < 16; ++k) {
        int j = j0 + k;
        v[k] = 0;
        if (j < M) {
            int b = j >> LOGC, c = j & maskC;
            v[k] = counts[(size_t)c * NBC + b];
        }
        p += v[k];
    }
    s[tid] = p; __syncthreads();
    for (int off = 1; off < 256; off <<= 1) {
        int u = (tid >= off) ? s[tid - off] : 0;
        __syncthreads();
        s[tid] += u;
        __syncthreads();
    }
    int run = bsums[blockIdx.x] + (s[tid] - p);
#pragma unroll
    for (int k = 0; k < 16; ++k) {
        int j = j0 + k;
        if (j < M) {
            base[j] = run;
            if ((j & maskC) == 0) bstart[j >> LOGC] = run;
            run += v[k];
        }
    }
}

// ---- scatter: block per chunk; XCD swizzle; coarse LDS cursors ------------
// rec = { col | T<<19 | nt<<22 , row & (CW-1) } (8B)
__global__ __launch_bounds__(512) void scatter_kernel(
    const int* __restrict__ ei, const int* __restrict__ etype,
    const int* __restrict__ ntype, const int* __restrict__ base,
    uint2* __restrict__ rec, int E, int NBC, int LOGC)
{
    __shared__ int cur[NBCMAX];
    int tid = threadIdx.x;
    // bijective XCD swizzle: consecutive chunks -> same XCD so straddle lines
    // between adjacent regions stay in one XCD's L2.
    int nwg = gridDim.x;
    int q = nwg >> 3, r = nwg & 7;
    int xcd = blockIdx.x & 7, idx = blockIdx.x >> 3;
    int c = (xcd < r) ? xcd * (q + 1) + idx
                      : r * (q + 1) + (xcd - r) * q + idx;
    for (int b = tid; b < NBC; b += 512)
        cur[b] = base[((size_t)b << LOGC) + c];
    __syncthreads();
    int s = c * CH, e = min(s + CH, E);
    for (int i = s + tid; i < e; i += 512) {
        int row = ei[i], col = ei[E + i];
        int T = etype[i], nt = ntype[col];
        int b = row >> CWSH;
        int slot = atomicAdd(&cur[b], 1);
        uint2 rc;
        rc.x = (unsigned)col | ((unsigned)T << 19) | ((unsigned)nt << 22);
        rc.y = (unsigned)(row & (CW - 1));
        rec[slot] = rc;
    }
}

// ---- consume: one block per (bucket, window); filter L2-resident region ---
// Sibling blocks (all 16 windows of a bucket) decode to the same bid%8 so
// they land on one XCD (heuristic round-robin dispatch) and share the
// region in that XCD's L2. No rec staging, no phases -> 36KB LDS, 4 blk/CU.
__global__ __launch_bounds__(256) void consume_kernel(
    const int* __restrict__ bstart, const uint2* __restrict__ rec,
    const float* __restrict__ x, const float* __restrict__ Wc,
    const int* __restrict__ batch, const float* __restrict__ inj,
    float* __restrict__ out, int N, int NBC, int PB)
{
    __shared__ float tile[WSZ * 57];    // 29184 B (stride 57: odd -> banks)
    __shared__ float Ws[55 * 32];       //  7040 B
    int tid = threadIdx.x;
    int lin = blockIdx.x >> 3;
    int b   = (blockIdx.x & 7) * PB + (lin >> NWSH);
    int w   = lin & (NW - 1);
    if (b >= NBC) return;
    int node0 = b * CW + w * WSZ;
    if (node0 >= N) return;

    for (int i = tid; i < 55 * 32; i += 256) Ws[i] = Wc[i];
    for (int i = tid; i < WSZ * 57 / 4; i += 256)
        ((float4*)tile)[i] = make_float4(0.f, 0.f, 0.f, 0.f);
    __syncthreads();

    int s = bstart[b], e = bstart[b + 1];
    for (int i = s + tid; i < e; i += 256) {
        uint2 rc = rec[i];
        if ((int)(rc.y >> 7) != w) continue;      // other window: skip
        int col  = rc.x & 0x7FFFF;
        int T    = (rc.x >> 19) & 7;
        int nt   = (rc.x >> 22) & 7;
        int lrow = (int)(rc.y & (WSZ - 1));
        float4 xv = ((const float4*)x)[col];
        float* tr = tile + lrow * 57 + T * 11;
        atomicAdd(tr + 0, xv.x);
        atomicAdd(tr + 1, xv.y);
        atomicAdd(tr + 2, xv.z);
        atomicAdd(tr + 3, xv.w);
        atomicAdd(tr + 4 + nt, 1.0f);
    }
    __syncthreads();

    int nodes = N - node0; if (nodes > WSZ) nodes = WSZ;
    for (int oi = tid; oi < nodes * 8; oi += 256) {
        int nl = oi >> 3, cq = oi & 7;
        int nn = node0 + nl;
        const float* ar = tile + nl * 57;
        float4 acc = {0.f, 0.f, 0.f, 0.f};
#pragma unroll 5
        for (int f = 0; f < 55; ++f) {
            float a = ar[f];
            float4 wv = *(const float4*)(Ws + f * 32 + cq * 4);
            acc.x += a * wv.x;
            acc.y += a * wv.y;
            acc.z += a * wv.z;
            acc.w += a * wv.w;
        }
        int bb = batch[nn];
        float4 iv = ((const float4*)inj)[bb * 8 + cq];
        float4 o;
        o.x = iv.x + 0.2f * acc.x;
        o.y = iv.y + 0.2f * acc.y;
        o.z = iv.z + 0.2f * acc.z;
        o.w = iv.w + 0.2f * acc.w;
        ((float4*)out)[(size_t)nn * 8 + cq] = o;
    }
}

// ---- fallback (guards fail): out init + direct atomic scatter -------------
__global__ __launch_bounds__(256) void init_kernel(
    const int* __restrict__ batch_id, const float* __restrict__ inj,
    float4* __restrict__ out, int N)
{
    int gid = blockIdx.x * 256 + threadIdx.x;
    if (gid >= N * 8) return;
    int n = gid >> 3, q = gid & 7;
    int b = batch_id[n];
    out[gid] = ((const float4*)inj)[b * 8 + q];
}

__global__ __launch_bounds__(256) void edge_direct_kernel(
    const int* __restrict__ ei, const int* __restrict__ etype,
    const int* __restrict__ ntype, const float* __restrict__ x,
    const float* __restrict__ Wc, float* __restrict__ out, int E)
{
    __shared__ float Ws[55 * 32];
    for (int i = threadIdx.x; i < 55 * 32; i += 256) Ws[i] = Wc[i];
    __syncthreads();
    unsigned total = (unsigned)E * 32u;
    unsigned stride = gridDim.x * 256u;
    for (unsigned idx = blockIdx.x * 256u + threadIdx.x; idx < total;
         idx += stride) {
        int e = (int)(idx >> 5);
        int c = (int)(idx & 31);
        int row = ei[e];
        int col = ei[E + e];
        int T = etype[e];
        int nt = ntype[col];
        float4 xv = ((const float4*)x)[col];
        const float* wb = Ws + T * 352;
        float y = xv.x * wb[c] + xv.y * wb[32 + c] + xv.z * wb[64 + c] +
                  xv.w * wb[96 + c] + wb[(4 + nt) * 32 + c];
        atomicAdd(out + (size_t)row * 32 + c, y * 0.2f);
    }
}

extern "C" void kernel_launch(void* const* d_in, const int* in_sizes, int n_in,
                              void* d_out, int out_size, void* d_ws, size_t ws_size,
                              hipStream_t stream) {
    const float* x     = (const float*)d_in[0];   // [N,4]
    const float* t     = (const float*)d_in[1];   // [8]
    const int*   ei    = (const int*)d_in[2];     // [2,E]
    const int*   etype = (const int*)d_in[3];     // [E]
    const int*   ntype = (const int*)d_in[4];     // [N]
    const int*   batch = (const int*)d_in[5];     // [N]
    const float* Wc    = (const float*)d_in[6];   // [55,32]
    const float* W1    = (const float*)d_in[7];   // [128,512]
    const float* b1    = (const float*)d_in[8];   // [512]
    const float* W2    = (const float*)d_in[9];   // [512,512]
    const float* b2    = (const float*)d_in[10];  // [512]
    const float* Wt    = (const float*)d_in[11];  // [512,32]
    float* out = (float*)d_out;

    int E = in_sizes[3];
    int N = in_sizes[4];

    int NBC = (N + CW - 1) >> CWSH;               // coarse buckets
    int PB  = (NBC + 7) >> 3;                     // buckets per XCD slot
    int NCH = (E + CH - 1) / CH;                  // real edge chunks
    int NCHP = 1, LOGC = 0;                       // padded to pow2
    while (NCHP < NCH) { NCHP <<= 1; ++LOGC; }
    size_t M = (size_t)NBC << LOGC;               // scan length
    int nblkA = (int)((M + 4095) / 4096);

    // ws layout (4-byte units)
    float* ws     = (float*)d_ws;
    float* h1acc  = ws;                           // 4096 (fallback only)
    float* h2acc  = ws + 4096;                    // 4096 (fallback only)
    float* inj    = ws + 8192;                    // 256
    int*   counts = (int*)(ws + 8448);            // M  (counts[c][b])
    int*   base   = counts + M;                   // M  (base[(b<<LOGC)+c])
    int*   bsums  = base + M;                     // 1024
    int*   bstart = bsums + 1024;                 // NBC+1
    size_t recOff = 8448 + 2 * M + 1024 + NBC + 1;
    recOff = (recOff + 1) & ~(size_t)1;           // 8B align
    uint2* rec    = (uint2*)(ws + recOff);        // E records (8B)

    size_t needBytes = (recOff + 2 * (size_t)E) * 4;
    bool okay = (NBC <= NBCMAX) && (nblkA <= 1024) && (ws_size >= needBytes) &&
                (N <= 524288) && (M < (size_t)1 << 30);

    if (okay) {
        temb_fused_kernel<<<8, 256, 0, stream>>>(t, W1, b1, W2, b2, Wt, inj);

        hist_kernel<<<NCHP, 256, 0, stream>>>(ei, counts, E, NBC);
        scanA_kernel<<<nblkA, 256, 0, stream>>>(counts, bsums, (int)M, NBC,
                                                LOGC);
        scanB_kernel<<<1, 1024, 0, stream>>>(bsums, bstart, nblkA, NBC, E);
        scanC_kernel<<<nblkA, 256, 0, stream>>>(counts, bsums, base, bstart,
                                                (int)M, NBC, LOGC);
        scatter_kernel<<<NCH, 512, 0, stream>>>(ei, etype, ntype, base, rec,
                                                E, NBC, LOGC);
        consume_kernel<<<8 * PB * NW, 256, 0, stream>>>(bstart, rec, x, Wc,
                                                        batch, inj, out,
                                                        N, NBC, PB);
    } else {
        hipMemsetAsync(d_ws, 0, 8448 * 4, stream);
        temb1_kernel<<<32, 64, 0, stream>>>(t, W1, h1acc);
        temb2_kernel<<<64, 64, 0, stream>>>(h1acc, b1, W2, h2acc);
        temb3_kernel<<<8, 256, 0, stream>>>(h2acc, b2, Wt, inj);
        init_kernel<<<(N * 8 + 255) / 256, 256, 0, stream>>>(
            batch, inj, (float4*)out, N);
        edge_direct_kernel<<<16384, 256, 0, stream>>>(
            ei, etype, ntype, x, Wc, out, E);
    }
}

// Round 7
// 364.187 us; speedup vs baseline: 1.0424x; 1.0424x over previous
//
#include <hip/hip_runtime.h>

// ---------------------------------------------------------------------------
// N=400000, E=2000000, B=8, C_IN=4, N_EDGE_TYPE=5, N_NODE_TYPE=7, C_OUT=32.
//
// HW model (measured, rounds 0-5):
//  - Global atomics into 88MB fp32 thrash L2: 504us (R1). DEAD END.
//  - Write-merge RULE: rec region >= ~8 recs, else write-allocate
//    amplification (R3: 141MB writes for 40MB payload).
//  - The 2M random x[col] gathers are THE stubborn cost. Consumer-side
//    placement is latency-bound at any occupancy (R2 105us full-wave,
//    R5 190us filtered 1/16-wave). Scatter-side placement is fine: R3's
//    scatter cost was region amplification, not the gather.
//  - Streaming phases and coarse regions are cheap; 16x L2 re-reads don't
//    show in FETCH (R5: 76MB) -> XCD L2 reuse works.
//  => R6 (resubmit; prior run died to infra): coarse sort (CW=2048, CH=4096,
//     ~21-rec regions) with scatter carrying x[col] into {meta u32, val
//     float4} records; REPACK pass fine-sorts each coarse region (16-way
//     hist+scan+cursor scatter, all sequential); consume streams contiguous
//     fine ranges -- zero random loads downstream of scatter.
// ---------------------------------------------------------------------------

#define CH      4096       // edges per chunk
#define CW      2048       // coarse bucket width (nodes)
#define CWSH    11         // log2(CW)
#define WSZ     128        // fine bucket / consume window (nodes)
#define NW      16         // fine buckets per coarse = CW/WSZ
#define NBCMAX  512        // max coarse buckets (N <= 1M)

// ---- temb fused: per-batch block computes emb->h1->h2->inj ----------------
__global__ __launch_bounds__(256) void temb_fused_kernel(
    const float* __restrict__ t,
    const float* __restrict__ W1, const float* __restrict__ b1,
    const float* __restrict__ W2, const float* __restrict__ b2,
    const float* __restrict__ Wt, float* __restrict__ inj)
{
    int b = blockIdx.x;
    int tid = threadIdx.x;
    __shared__ float emb[128];
    __shared__ float s1[512];
    __shared__ float s2[512];
    __shared__ float red[256];
    float tv = t[b];
    if (tid < 128) {
        const float kStep = 9.210340371976184f / 63.0f;
        int k = tid & 63;
        float ang = tv * expf(-(float)k * kStep);
        emb[tid] = (tid < 64) ? sinf(ang) : cosf(ang);
    }
    __syncthreads();
    {
        float a0 = 0.f, a1 = 0.f;
        for (int k = 0; k < 128; ++k) {
            float e = emb[k];
            a0 += e * W1[k * 512 + tid];
            a1 += e * W1[k * 512 + tid + 256];
        }
        float v0 = a0 + b1[tid], v1 = a1 + b1[tid + 256];
        s1[tid]       = v0 / (1.0f + expf(-v0));
        s1[tid + 256] = v1 / (1.0f + expf(-v1));
    }
    __syncthreads();
    {
        float a0 = 0.f, a1 = 0.f;
        for (int k = 0; k < 512; ++k) {
            float e = s1[k];
            a0 += e * W2[k * 512 + tid];
            a1 += e * W2[k * 512 + tid + 256];
        }
        float v0 = a0 + b2[tid], v1 = a1 + b2[tid + 256];
        s2[tid]       = v0 / (1.0f + expf(-v0));
        s2[tid + 256] = v1 / (1.0f + expf(-v1));
    }
    __syncthreads();
    {
        int c = tid & 31, seg = tid >> 5;
        float acc = 0.f;
        int k0 = seg * 64;
        for (int k = k0; k < k0 + 64; ++k)
            acc += s2[k] * Wt[k * 32 + c];
        red[tid] = acc;
        __syncthreads();
        if (tid < 32) {
            float s = 0.f;
#pragma unroll
            for (int g = 0; g < 8; ++g) s += red[g * 32 + tid];
            inj[b * 32 + tid] = s;
        }
    }
}

// ---- legacy temb kernels (fallback path only) -----------------------------
__global__ __launch_bounds__(64) void temb1_kernel(
    const float* __restrict__ t, const float* __restrict__ W1,
    float* __restrict__ h1acc)
{
    int jb = blockIdx.x & 7, ks = blockIdx.x >> 3;
    __shared__ float embs[8][32];
    int tid = threadIdx.x;
    const float kStep = 9.210340371976184f / 63.0f;
    for (int i = tid; i < 256; i += 64) {
        int b = i >> 5, kk = i & 31;
        int k = ks * 32 + kk;
        float v;
        if (k < 64) v = sinf(t[b] * expf(-(float)k * kStep));
        else        v = cosf(t[b] * expf(-(float)(k - 64) * kStep));
        embs[b][kk] = v;
    }
    __syncthreads();
    int j = jb * 64 + tid;
    float acc[8] = {};
    for (int kk = 0; kk < 32; ++kk) {
        float w = W1[(ks * 32 + kk) * 512 + j];
#pragma unroll
        for (int b = 0; b < 8; ++b) acc[b] += embs[b][kk] * w;
    }
#pragma unroll
    for (int b = 0; b < 8; ++b) atomicAdd(&h1acc[b * 512 + j], acc[b]);
}

__global__ __launch_bounds__(64) void temb2_kernel(
    const float* __restrict__ h1acc, const float* __restrict__ b1,
    const float* __restrict__ W2, float* __restrict__ h2acc)
{
    int jb = blockIdx.x & 7, ks = blockIdx.x >> 3;
    __shared__ float h1s[8][64];
    int tid = threadIdx.x;
    for (int i = tid; i < 512; i += 64) {
        int b = i >> 6, kk = i & 63;
        int k = ks * 64 + kk;
        float v = h1acc[b * 512 + k] + b1[k];
        h1s[b][kk] = v / (1.0f + expf(-v));
    }
    __syncthreads();
    int j = jb * 64 + tid;
    float acc[8] = {};
    for (int kk = 0; kk < 64; ++kk) {
        float w = W2[(ks * 64 + kk) * 512 + j];
#pragma unroll
        for (int b = 0; b < 8; ++b) acc[b] += h1s[b][kk] * w;
    }
#pragma unroll
    for (int b = 0; b < 8; ++b) atomicAdd(&h2acc[b * 512 + j], acc[b]);
}

__global__ __launch_bounds__(256) void temb3_kernel(
    const float* __restrict__ h2acc, const float* __restrict__ b2,
    const float* __restrict__ Wt, float* __restrict__ inj)
{
    int ks = blockIdx.x;
    __shared__ float sws[8][64];
    int tid = threadIdx.x;
    for (int i = tid; i < 512; i += 256) {
        int b = i >> 6, kk = i & 63;
        int k = ks * 64 + kk;
        float v = h2acc[b * 512 + k] + b2[k];
        sws[b][kk] = v / (1.0f + expf(-v));
    }
    __syncthreads();
    int b = tid >> 5, c = tid & 31;
    float acc = 0.f;
    for (int kk = 0; kk < 64; ++kk)
        acc += sws[b][kk] * Wt[(ks * 64 + kk) * 32 + c];
    atomicAdd(&inj[tid], acc);
}

// ---- hist: block per chunk (grid NCHP); coarse LDS histogram --------------
// counts layout: counts[c * NBC + b]
__global__ __launch_bounds__(256) void hist_kernel(
    const int* __restrict__ ei, int* __restrict__ counts, int E, int NBC)
{
    __shared__ int h[NBCMAX];
    int tid = threadIdx.x;
    int c = blockIdx.x;
    for (int i = tid; i < NBC; i += 256) h[i] = 0;
    __syncthreads();
    int s = c * CH, e = min(s + CH, E);
    for (int i = s + tid; i < e; i += 256)
        atomicAdd(&h[ei[i] >> CWSH], 1);
    __syncthreads();
    int* row = counts + (size_t)c * NBC;
    for (int i = tid; i < NBC; i += 256) row[i] = h[i];
}

// ---- scanA: per-block sums over j = (b<<LOGC)+c order ---------------------
__global__ __launch_bounds__(256) void scanA_kernel(
    const int* __restrict__ counts, int* __restrict__ bsums,
    int M, int NBC, int LOGC)
{
    __shared__ int s[256];
    int tid = threadIdx.x;
    int j0 = blockIdx.x * 4096 + tid * 16;
    int maskC = (1 << LOGC) - 1;
    int p = 0;
#pragma unroll
    for (int k = 0; k < 16; ++k) {
        int j = j0 + k;
        if (j < M) {
            int b = j >> LOGC, c = j & maskC;
            p += counts[(size_t)c * NBC + b];
        }
    }
    s[tid] = p; __syncthreads();
    for (int off = 128; off > 0; off >>= 1) {
        if (tid < off) s[tid] += s[tid + off];
        __syncthreads();
    }
    if (tid == 0) bsums[blockIdx.x] = s[0];
}

// ---- scanB: exclusive scan of block sums (single block, <=1024) -----------
__global__ __launch_bounds__(1024) void scanB_kernel(
    int* __restrict__ bsums, int* __restrict__ bstart, int nblk, int NBC, int E)
{
    __shared__ int s[1024];
    int tid = threadIdx.x;
    int v = (tid < nblk) ? bsums[tid] : 0;
    s[tid] = v; __syncthreads();
    for (int off = 1; off < 1024; off <<= 1) {
        int u = (tid >= off) ? s[tid - off] : 0;
        __syncthreads();
        s[tid] += u;
        __syncthreads();
    }
    if (tid < nblk) bsums[tid] = s[tid] - v;          // exclusive
    if (tid == 0) bstart[NBC] = E;
}

// ---- scanC: exact base for every (bucket, chunk) region + bstart ----------
// base layout: base[(b<<LOGC)+c] (linear in scan order)
__global__ __launch_bounds__(256) void scanC_kernel(
    const int* __restrict__ counts, const int* __restrict__ bsums,
    int* __restrict__ base, int* __restrict__ bstart,
    int M, int NBC, int LOGC)
{
    __shared__ int s[256];
    int tid = threadIdx.x;
    int j0 = blockIdx.x * 4096 + tid * 16;
    int maskC = (1 << LOGC) - 1;
    int v[16]; int p = 0;
#pragma unroll
    for (int k = 0; k < 16; ++k) {
        int j = j0 + k;
        v[k] = 0;
        if (j < M) {
            int b = j >> LOGC, c = j & maskC;
            v[k] = counts[(size_t)c * NBC + b];
        }
        p += v[k];
    }
    s[tid] = p; __syncthreads();
    for (int off = 1; off < 256; off <<= 1) {
        int u = (tid >= off) ? s[tid - off] : 0;
        __syncthreads();
        s[tid] += u;
        __syncthreads();
    }
    int run = bsums[blockIdx.x] + (s[tid] - p);
#pragma unroll
    for (int k = 0; k < 16; ++k) {
        int j = j0 + k;
        if (j < M) {
            base[j] = run;
            if ((j & maskC) == 0) bstart[j >> LOGC] = run;
            run += v[k];
        }
    }
}

// ---- scatter: block per chunk; XCD swizzle; coarse cursors; CARRIES x -----
// meta = (row & 2047) | T<<11 | nt<<14 ; val = x[col]
__global__ __launch_bounds__(512) void scatter_kernel(
    const int* __restrict__ ei, const int* __restrict__ etype,
    const int* __restrict__ ntype, const float* __restrict__ x,
    const int* __restrict__ base,
    unsigned* __restrict__ recMeta, float4* __restrict__ recVal,
    int E, int NBC, int LOGC)
{
    __shared__ int cur[NBCMAX];
    int tid = threadIdx.x;
    // bijective XCD swizzle: consecutive chunks -> same XCD so boundary lines
    // between adjacent regions stay in one XCD's L2.
    int nwg = gridDim.x;
    int q = nwg >> 3, r = nwg & 7;
    int xcd = blockIdx.x & 7, idx = blockIdx.x >> 3;
    int c = (xcd < r) ? xcd * (q + 1) + idx
                      : r * (q + 1) + (xcd - r) * q + idx;
    for (int b = tid; b < NBC; b += 512)
        cur[b] = base[((size_t)b << LOGC) + c];
    __syncthreads();
    int s = c * CH, e = min(s + CH, E);
    for (int i = s + tid; i < e; i += 512) {
        int row = ei[i], col = ei[E + i];
        int T = etype[i], nt = ntype[col];
        float4 xv = ((const float4*)x)[col];
        int b = row >> CWSH;
        int slot = atomicAdd(&cur[b], 1);
        recMeta[slot] = (unsigned)(row & (CW - 1)) |
                        ((unsigned)T << 11) | ((unsigned)nt << 14);
        recVal[slot] = xv;
    }
}

// ---- repack: block per coarse bucket; fine-sort region (seq traffic) ------
__global__ __launch_bounds__(512) void repack_kernel(
    const int* __restrict__ bstartC,
    const unsigned* __restrict__ meta, const float4* __restrict__ val,
    unsigned* __restrict__ meta2, float4* __restrict__ val2,
    int* __restrict__ fineStart)
{
    __shared__ int h[NW], cur[NW], segb[NW];
    int b = blockIdx.x;
    int tid = threadIdx.x;
    if (tid < NW) h[tid] = 0;
    __syncthreads();
    int s = bstartC[b], e = bstartC[b + 1];
    for (int i = s + tid; i < e; i += 512) {
        int w = (int)((meta[i] & (CW - 1)) >> 7);
        atomicAdd(&h[w], 1);
    }
    __syncthreads();
    if (tid == 0) {
        int run = s;
#pragma unroll
        for (int w = 0; w < NW; ++w) { segb[w] = run; run += h[w]; }
    }
    __syncthreads();
    if (tid < NW) {
        cur[tid] = segb[tid];
        fineStart[b * NW + tid] = segb[tid];
    }
    __syncthreads();
    for (int i = s + tid; i < e; i += 512) {
        unsigned m = meta[i];
        float4 v = val[i];
        int w = (int)((m & (CW - 1)) >> 7);
        int slot = atomicAdd(&cur[w], 1);
        meta2[slot] = m;
        val2[slot] = v;
    }
}

// ---- consume: block per fine bucket; PURE STREAMING; LDS acc; dense mix ---
__global__ __launch_bounds__(256) void consume_kernel(
    const int* __restrict__ fineStart, const unsigned* __restrict__ meta2,
    const float4* __restrict__ val2, const float* __restrict__ Wc,
    const int* __restrict__ batch, const float* __restrict__ inj,
    float* __restrict__ out, int N, int NF, int E)
{
    __shared__ float tile[WSZ * 57];    // 29184 B (stride 57: odd -> banks)
    __shared__ float Ws[55 * 32];       //  7040 B
    int tid = threadIdx.x;
    int f = blockIdx.x;
    int node0 = f * WSZ;
    if (node0 >= N) return;

    for (int i = tid; i < 55 * 32; i += 256) Ws[i] = Wc[i];
    for (int i = tid; i < WSZ * 57 / 4; i += 256)
        ((float4*)tile)[i] = make_float4(0.f, 0.f, 0.f, 0.f);
    __syncthreads();

    int s = fineStart[f];
    int e = (f == NF - 1) ? E : fineStart[f + 1];
#pragma unroll 2
    for (int i = s + tid; i < e; i += 256) {
        unsigned m = meta2[i];
        float4 xv = val2[i];
        int lrow = (int)(m & (WSZ - 1));
        int T    = (int)((m >> 11) & 7);
        int nt   = (int)((m >> 14) & 7);
        float* tr = tile + lrow * 57 + T * 11;
        atomicAdd(tr + 0, xv.x);
        atomicAdd(tr + 1, xv.y);
        atomicAdd(tr + 2, xv.z);
        atomicAdd(tr + 3, xv.w);
        atomicAdd(tr + 4 + nt, 1.0f);
    }
    __syncthreads();

    int nodes = N - node0; if (nodes > WSZ) nodes = WSZ;
    for (int oi = tid; oi < nodes * 8; oi += 256) {
        int nl = oi >> 3, cq = oi & 7;
        int nn = node0 + nl;
        const float* ar = tile + nl * 57;
        float4 acc = {0.f, 0.f, 0.f, 0.f};
#pragma unroll 5
        for (int fk = 0; fk < 55; ++fk) {
            float a = ar[fk];
            float4 wv = *(const float4*)(Ws + fk * 32 + cq * 4);
            acc.x += a * wv.x;
            acc.y += a * wv.y;
            acc.z += a * wv.z;
            acc.w += a * wv.w;
        }
        int bb = batch[nn];
        float4 iv = ((const float4*)inj)[bb * 8 + cq];
        float4 o;
        o.x = iv.x + 0.2f * acc.x;
        o.y = iv.y + 0.2f * acc.y;
        o.z = iv.z + 0.2f * acc.z;
        o.w = iv.w + 0.2f * acc.w;
        ((float4*)out)[(size_t)nn * 8 + cq] = o;
    }
}

// ---- fallback (guards fail): out init + direct atomic scatter -------------
__global__ __launch_bounds__(256) void init_kernel(
    const int* __restrict__ batch_id, const float* __restrict__ inj,
    float4* __restrict__ out, int N)
{
    int gid = blockIdx.x * 256 + threadIdx.x;
    if (gid >= N * 8) return;
    int n = gid >> 3, q = gid & 7;
    int b = batch_id[n];
    out[gid] = ((const float4*)inj)[b * 8 + q];
}

__global__ __launch_bounds__(256) void edge_direct_kernel(
    const int* __restrict__ ei, const int* __restrict__ etype,
    const int* __restrict__ ntype, const float* __restrict__ x,
    const float* __restrict__ Wc, float* __restrict__ out, int E)
{
    __shared__ float Ws[55 * 32];
    for (int i = threadIdx.x; i < 55 * 32; i += 256) Ws[i] = Wc[i];
    __syncthreads();
    unsigned total = (unsigned)E * 32u;
    unsigned stride = gridDim.x * 256u;
    for (unsigned idx = blockIdx.x * 256u + threadIdx.x; idx < total;
         idx += stride) {
        int e = (int)(idx >> 5);
        int c = (int)(idx & 31);
        int row = ei[e];
        int col = ei[E + e];
        int T = etype[e];
        int nt = ntype[col];
        float4 xv = ((const float4*)x)[col];
        const float* wb = Ws + T * 352;
        float y = xv.x * wb[c] + xv.y * wb[32 + c] + xv.z * wb[64 + c] +
                  xv.w * wb[96 + c] + wb[(4 + nt) * 32 + c];
        atomicAdd(out + (size_t)row * 32 + c, y * 0.2f);
    }
}

extern "C" void kernel_launch(void* const* d_in, const int* in_sizes, int n_in,
                              void* d_out, int out_size, void* d_ws, size_t ws_size,
                              hipStream_t stream) {
    const float* x     = (const float*)d_in[0];   // [N,4]
    const float* t     = (const float*)d_in[1];   // [8]
    const int*   ei    = (const int*)d_in[2];     // [2,E]
    const int*   etype = (const int*)d_in[3];     // [E]
    const int*   ntype = (const int*)d_in[4];     // [N]
    const int*   batch = (const int*)d_in[5];     // [N]
    const float* Wc    = (const float*)d_in[6];   // [55,32]
    const float* W1    = (const float*)d_in[7];   // [128,512]
    const float* b1    = (const float*)d_in[8];   // [512]
    const float* W2    = (const float*)d_in[9];   // [512,512]
    const float* b2    = (const float*)d_in[10];  // [512]
    const float* Wt    = (const float*)d_in[11];  // [512,32]
    float* out = (float*)d_out;

    int E = in_sizes[3];
    int N = in_sizes[4];

    int NBC = (N + CW - 1) >> CWSH;               // coarse buckets
    int NF  = NBC * NW;                           // fine buckets
    int NCH = (E + CH - 1) / CH;                  // real edge chunks
    int NCHP = 1, LOGC = 0;                       // padded to pow2
    while (NCHP < NCH) { NCHP <<= 1; ++LOGC; }
    size_t M = (size_t)NBC << LOGC;               // scan length
    int nblkA = (int)((M + 4095) / 4096);

    // ws layout (4-byte units)
    float* ws     = (float*)d_ws;
    float* h1acc  = ws;                           // 4096 (fallback only)
    float* h2acc  = ws + 4096;                    // 4096 (fallback only)
    float* inj    = ws + 8192;                    // 256
    int*   counts = (int*)(ws + 8448);            // M  (counts[c][b])
    int*   base   = counts + M;                   // M  (base[(b<<LOGC)+c])
    int*   bsums  = base + M;                     // 1024
    int*   bstart = bsums + 1024;                 // NBC+1
    int*   fineSt = bstart + NBC + 1;             // NF
    size_t mOff = 8448 + 2 * M + 1024 + (NBC + 1) + NF;
    mOff = (mOff + 3) & ~(size_t)3;               // 16B align
    unsigned* recMeta  = (unsigned*)(ws + mOff);            // E
    size_t v1Off = (mOff + (size_t)E + 3) & ~(size_t)3;
    float4*   recVal   = (float4*)(ws + v1Off);             // 4E
    size_t m2Off = v1Off + 4 * (size_t)E;
    unsigned* recMeta2 = (unsigned*)(ws + m2Off);           // E
    size_t v2Off = (m2Off + (size_t)E + 3) & ~(size_t)3;
    float4*   recVal2  = (float4*)(ws + v2Off);             // 4E

    size_t needBytes = (v2Off + 4 * (size_t)E) * 4;
    bool okay = (NBC <= NBCMAX) && (nblkA <= 1024) && (ws_size >= needBytes) &&
                (N <= 524288) && (M < (size_t)1 << 30);

    if (okay) {
        temb_fused_kernel<<<8, 256, 0, stream>>>(t, W1, b1, W2, b2, Wt, inj);

        hist_kernel<<<NCHP, 256, 0, stream>>>(ei, counts, E, NBC);
        scanA_kernel<<<nblkA, 256, 0, stream>>>(counts, bsums, (int)M, NBC,
                                                LOGC);
        scanB_kernel<<<1, 1024, 0, stream>>>(bsums, bstart, nblkA, NBC, E);
        scanC_kernel<<<nblkA, 256, 0, stream>>>(counts, bsums, base, bstart,
                                                (int)M, NBC, LOGC);
        scatter_kernel<<<NCH, 512, 0, stream>>>(ei, etype, ntype, x, base,
                                                recMeta, recVal, E, NBC, LOGC);
        repack_kernel<<<NBC, 512, 0, stream>>>(bstart, recMeta, recVal,
                                               recMeta2, recVal2, fineSt);
        consume_kernel<<<NF, 256, 0, stream>>>(fineSt, recMeta2, recVal2, Wc,
                                               batch, inj, out, N, NF, E);
    } else {
        hipMemsetAsync(d_ws, 0, 8448 * 4, stream);
        temb1_kernel<<<32, 64, 0, stream>>>(t, W1, h1acc);
        temb2_kernel<<<64, 64, 0, stream>>>(h1acc, b1, W2, h2acc);
        temb3_kernel<<<8, 256, 0, stream>>>(h2acc, b2, Wt, inj);
        init_kernel<<<(N * 8 + 255) / 256, 256, 0, stream>>>(
            batch, inj, (float4*)out, N);
        edge_direct_kernel<<<16384, 256, 0, stream>>>(
            ei, etype, ntype, x, Wc, out, E);
    }
}

// Round 8
// 261.526 us; speedup vs baseline: 1.4516x; 1.3925x over previous
//
#include <hip/hip_runtime.h>

// ---------------------------------------------------------------------------
// N=400000, E=2000000, B=8, C_IN=4, N_EDGE_TYPE=5, N_NODE_TYPE=7, C_OUT=32.
//
// HW model (measured, rounds 0-7):
//  - Global atomics into 88MB fp32 thrash L2: 504us (R1). DEAD END.
//  - Write-merge RULE: multi-XCD sub-line writes amplify (R3); single-BLOCK
//    scattered writes are absorbed by that XCD's L2 (no amplification).
//  - consume is NOT gather-bound (R7: zero random loads, still 101us).
//    It is epilogue-LDS + serial-structure bound: 440 LDS ops/thread for
//    the dense mix, all pipes individually <25us.
//  - temb as one 8-block kernel = ~30us serial at stream head.
//  => R8: (1) epilogue: thread=(node,ch-half), Wc via wave-uniform
//     readfirstlane -> s_load (SMEM pipe), 55 LDS reads/thread, no Ws
//     staging; (2) temb stages ride as extra blocks on hist/scanA/scanC;
//     (3) 4-byte records (col|T|nt|lrow7), x-gather back in consume;
//     single-pass repack from hist-computed fine counts.
// ---------------------------------------------------------------------------

#define CH      4096       // edges per chunk
#define CW      2048       // coarse bucket width (nodes)
#define CWSH    11         // log2(CW)
#define WSZ     128        // fine bucket / consume window (nodes)
#define WSH     7          // log2(WSZ)
#define NW      16         // fine per coarse = CW/WSZ
#define NBCMAX  512        // max coarse buckets
#define NFPMAX  8192       // max padded fine buckets (LDS hist)

// ---- histW: chunk blocks do fine LDS hist (+ coarse rows + replica merge);
// ---- extra 8 blocks do temb stage1 (h1 = emb@W1, zero h2acc/inj) ----------
__global__ __launch_bounds__(256) void histW_kernel(
    const int* __restrict__ ei, int* __restrict__ counts,
    int* __restrict__ fineRep,
    const float* __restrict__ t, const float* __restrict__ W1,
    float* __restrict__ h1acc, float* __restrict__ h2acc,
    float* __restrict__ inj,
    int E, int NBC, int NFp, int NCHP)
{
    int tid = threadIdx.x;
    if ((int)blockIdx.x >= NCHP) {
        int b = blockIdx.x - NCHP;
        __shared__ float emb[128];
        if (tid < 128) {
            const float kStep = 9.210340371976184f / 63.0f;
            int k = tid & 63;
            float ang = t[b] * expf(-(float)k * kStep);
            emb[tid] = (tid < 64) ? sinf(ang) : cosf(ang);
        }
        __syncthreads();
        for (int j = tid; j < 512; j += 256) {
            float a = 0.f;
            for (int k = 0; k < 128; ++k) a += emb[k] * W1[k * 512 + j];
            h1acc[b * 512 + j] = a;        // pre-bias/swish
            h2acc[b * 512 + j] = 0.f;
        }
        if (tid < 32) inj[b * 32 + tid] = 0.f;
        return;
    }
    __shared__ int fh[NFPMAX];
    int c = blockIdx.x;
    for (int i = tid; i < NFp; i += 256) fh[i] = 0;
    __syncthreads();
    int s = c * CH, e = min(s + CH, E);
    for (int i = s + tid; i < e; i += 256)
        atomicAdd(&fh[ei[i] >> WSH], 1);
    __syncthreads();
    int* row = counts + (size_t)c * NBC;
    for (int b = tid; b < NBC; b += 256) {
        int sum = 0;
#pragma unroll
        for (int w = 0; w < NW; ++w) sum += fh[b * NW + w];
        row[b] = sum;
    }
    int* rep = fineRep + (size_t)(blockIdx.x & 7) * NFp;
    for (int i = tid; i < NFp; i += 256) {
        int v = fh[i];
        if (v) atomicAdd(&rep[i], v);
    }
}

// ---- scanA: per-block sums (j=(b<<LOGC)+c); extra 64 blocks = temb stage2 -
__global__ __launch_bounds__(256) void scanA_kernel(
    const int* __restrict__ counts, int* __restrict__ bsums,
    const float* __restrict__ h1acc, const float* __restrict__ b1,
    const float* __restrict__ W2, float* __restrict__ h2acc,
    int M, int NBC, int LOGC, int nblkA)
{
    int tid = threadIdx.x;
    if ((int)blockIdx.x >= nblkA) {
        int p = blockIdx.x - nblkA;            // k-slice [8p, 8p+8)
        __shared__ float h1s[64];              // [b*8+kk]
        if (tid < 64) {
            int bb = tid >> 3, kk = tid & 7;
            int k = p * 8 + kk;
            float v = h1acc[bb * 512 + k] + b1[k];
            h1s[tid] = v / (1.f + expf(-v));
        }
        __syncthreads();
        for (int jj = 0; jj < 2; ++jj) {
            int j = tid + jj * 256;
            float acc[8] = {};
#pragma unroll
            for (int kk = 0; kk < 8; ++kk) {
                float w = W2[(p * 8 + kk) * 512 + j];
#pragma unroll
                for (int bb = 0; bb < 8; ++bb) acc[bb] += h1s[bb * 8 + kk] * w;
            }
#pragma unroll
            for (int bb = 0; bb < 8; ++bb)
                atomicAdd(&h2acc[bb * 512 + j], acc[bb]);
        }
        return;
    }
    __shared__ int s[256];
    int j0 = blockIdx.x * 4096 + tid * 16;
    int maskC = (1 << LOGC) - 1;
    int p = 0;
#pragma unroll
    for (int k = 0; k < 16; ++k) {
        int j = j0 + k;
        if (j < M) {
            int b = j >> LOGC, c = j & maskC;
            p += counts[(size_t)c * NBC + b];
        }
    }
    s[tid] = p; __syncthreads();
    for (int off = 128; off > 0; off >>= 1) {
        if (tid < off) s[tid] += s[tid + off];
        __syncthreads();
    }
    if (tid == 0) bsums[blockIdx.x] = s[0];
}

// ---- scanBF: 1 block: coarse block-sum scan + fine exclusive scan ---------
__global__ __launch_bounds__(1024) void scanBF_kernel(
    int* __restrict__ bsums, int* __restrict__ bstart,
    const int* __restrict__ fineRep, int* __restrict__ fineStart,
    int nblk, int NBC, int NFp, int E)
{
    __shared__ int s[1024];
    __shared__ int fs[1024];
    int tid = threadIdx.x;
    int v = (tid < nblk) ? bsums[tid] : 0;
    s[tid] = v; __syncthreads();
    for (int off = 1; off < 1024; off <<= 1) {
        int u = (tid >= off) ? s[tid - off] : 0;
        __syncthreads();
        s[tid] += u;
        __syncthreads();
    }
    if (tid < nblk) bsums[tid] = s[tid] - v;          // exclusive
    if (tid == 0) bstart[NBC] = E;
    // ---- fine scan ----
    int PTF = (NFp + 1023) >> 10;
    int b0 = tid * PTF;
    int run = 0;
    for (int q = 0; q < PTF; ++q) {
        int i = b0 + q;
        if (i < NFp) {
            int csum = 0;
#pragma unroll
            for (int r = 0; r < 8; ++r) csum += fineRep[(size_t)r * NFp + i];
            run += csum;
        }
    }
    fs[tid] = run; __syncthreads();
    for (int off = 1; off < 1024; off <<= 1) {
        int u = (tid >= off) ? fs[tid - off] : 0;
        __syncthreads();
        fs[tid] += u;
        __syncthreads();
    }
    int tbase = fs[tid] - run;
    for (int q = 0; q < PTF; ++q) {
        int i = b0 + q;
        if (i < NFp) {
            int csum = 0;
#pragma unroll
            for (int r = 0; r < 8; ++r) csum += fineRep[(size_t)r * NFp + i];
            fineStart[i] = tbase;
            tbase += csum;
        }
    }
    if (tid == 0) fineStart[NFp] = E;
}

// ---- scanC: per-(bucket,chunk) bases + bstart; extra 8 blocks = stage3 ----
__global__ __launch_bounds__(256) void scanC_kernel(
    const int* __restrict__ counts, const int* __restrict__ bsums,
    int* __restrict__ base, int* __restrict__ bstart,
    const float* __restrict__ h2acc, const float* __restrict__ b2,
    const float* __restrict__ Wt, float* __restrict__ inj,
    int M, int NBC, int LOGC, int nblkA)
{
    int tid = threadIdx.x;
    if ((int)blockIdx.x >= nblkA) {
        int ks = blockIdx.x - nblkA;
        __shared__ float sws[8][64];
        for (int i = tid; i < 512; i += 256) {
            int b = i >> 6, kk = i & 63;
            int k = ks * 64 + kk;
            float v = h2acc[b * 512 + k] + b2[k];
            sws[b][kk] = v / (1.f + expf(-v));
        }
        __syncthreads();
        int b = tid >> 5, c = tid & 31;
        float acc = 0.f;
        for (int kk = 0; kk < 64; ++kk)
            acc += sws[b][kk] * Wt[(ks * 64 + kk) * 32 + c];
        atomicAdd(&inj[tid], acc);
        return;
    }
    __shared__ int s[256];
    int j0 = blockIdx.x * 4096 + tid * 16;
    int maskC = (1 << LOGC) - 1;
    int v[16]; int p = 0;
#pragma unroll
    for (int k = 0; k < 16; ++k) {
        int j = j0 + k;
        v[k] = 0;
        if (j < M) {
            int b = j >> LOGC, c = j & maskC;
            v[k] = counts[(size_t)c * NBC + b];
        }
        p += v[k];
    }
    s[tid] = p; __syncthreads();
    for (int off = 1; off < 256; off <<= 1) {
        int u = (tid >= off) ? s[tid - off] : 0;
        __syncthreads();
        s[tid] += u;
        __syncthreads();
    }
    int run = bsums[blockIdx.x] + (s[tid] - p);
#pragma unroll
    for (int k = 0; k < 16; ++k) {
        int j = j0 + k;
        if (j < M) {
            base[j] = run;
            if ((j & maskC) == 0) bstart[j >> LOGC] = run;
            run += v[k];
        }
    }
}

// ---- scatter: block per chunk; XCD swizzle; coarse LDS cursors; 8B recs ---
// rec = { col | T<<19 | nt<<22 , row & (CW-1) }
__global__ __launch_bounds__(512) void scatter_kernel(
    const int* __restrict__ ei, const int* __restrict__ etype,
    const int* __restrict__ ntype, const int* __restrict__ base,
    uint2* __restrict__ rec, int E, int NBC, int LOGC)
{
    __shared__ int cur[NBCMAX];
    int tid = threadIdx.x;
    int nwg = gridDim.x;
    int q = nwg >> 3, r = nwg & 7;
    int xcd = blockIdx.x & 7, idx = blockIdx.x >> 3;
    int c = (xcd < r) ? xcd * (q + 1) + idx
                      : r * (q + 1) + (xcd - r) * q + idx;
    for (int b = tid; b < NBC; b += 512)
        cur[b] = base[((size_t)b << LOGC) + c];
    __syncthreads();
    int s = c * CH, e = min(s + CH, E);
    for (int i = s + tid; i < e; i += 512) {
        int row = ei[i], col = ei[E + i];
        int T = etype[i], nt = ntype[col];
        int b = row >> CWSH;
        int slot = atomicAdd(&cur[b], 1);
        uint2 rc;
        rc.x = (unsigned)col | ((unsigned)T << 19) | ((unsigned)nt << 22);
        rc.y = (unsigned)(row & (CW - 1));
        rec[slot] = rc;
    }
}

// ---- repack: block per coarse bucket; single pass -> 4B fine-sorted recs --
__global__ __launch_bounds__(1024) void repack_kernel(
    const int* __restrict__ bstart, const int* __restrict__ fineStart,
    const uint2* __restrict__ rec, unsigned* __restrict__ rec2)
{
    __shared__ int cur[NW];
    int tid = threadIdx.x;
    int b = blockIdx.x;
    if (tid < NW) cur[tid] = fineStart[b * NW + tid];
    __syncthreads();
    int s = bstart[b], e = bstart[b + 1];
    for (int i = s + tid; i < e; i += 1024) {
        uint2 rc = rec[i];
        int w = (int)(rc.y >> WSH);
        int slot = atomicAdd(&cur[w], 1);
        rec2[slot] = rc.x | ((rc.y & (WSZ - 1)) << 25);
    }
}

// ---- consume: block per fine bucket; gather + LDS acc; SGPR-Wc epilogue ---
__global__ __launch_bounds__(256) void consume_kernel(
    const int* __restrict__ fineStart, const unsigned* __restrict__ rec2,
    const float* __restrict__ x, const float* __restrict__ Wc,
    const int* __restrict__ batch, const float* __restrict__ inj,
    float* __restrict__ out, int N)
{
    __shared__ __align__(16) float tile[WSZ * 57];  // 29184 B
    int tid = threadIdx.x;
    int f = blockIdx.x;
    int node0 = f << WSH;

    for (int i = tid; i < WSZ * 57 / 4; i += 256)
        ((float4*)tile)[i] = make_float4(0.f, 0.f, 0.f, 0.f);
    __syncthreads();

    int s = fineStart[f], e = fineStart[f + 1];
    for (int i = s + tid; i < e; i += 256) {
        unsigned u = rec2[i];
        int col  = (int)(u & 0x7FFFFu);
        int T    = (int)((u >> 19) & 7u);
        int nt   = (int)((u >> 22) & 7u);
        int lrow = (int)(u >> 25);
        float4 xv = ((const float4*)x)[col];
        float* tr = tile + lrow * 57 + T * 11;
        atomicAdd(tr + 0, xv.x);
        atomicAdd(tr + 1, xv.y);
        atomicAdd(tr + 2, xv.z);
        atomicAdd(tr + 3, xv.w);
        atomicAdd(tr + 4 + nt, 1.0f);
    }
    __syncthreads();

    int nodes = N - node0; if (nodes > WSZ) nodes = WSZ;
    int nl = tid & (WSZ - 1);
    int hf = __builtin_amdgcn_readfirstlane((int)tid >> 7);  // wave-uniform
    if (nl < nodes) {
        const float* ar = tile + nl * 57;
        const float4* wb = ((const float4*)Wc) + hf * 4;     // uniform base
        float4 a0 = {0.f,0.f,0.f,0.f}, a1 = a0, a2 = a0, a3 = a0;
#pragma unroll 5
        for (int k = 0; k < 55; ++k) {
            float a = ar[k];
            float4 w0 = wb[k * 8 + 0];
            float4 w1 = wb[k * 8 + 1];
            float4 w2 = wb[k * 8 + 2];
            float4 w3 = wb[k * 8 + 3];
            a0.x += a * w0.x; a0.y += a * w0.y; a0.z += a * w0.z; a0.w += a * w0.w;
            a1.x += a * w1.x; a1.y += a * w1.y; a1.z += a * w1.z; a1.w += a * w1.w;
            a2.x += a * w2.x; a2.y += a * w2.y; a2.z += a * w2.z; a2.w += a * w2.w;
            a3.x += a * w3.x; a3.y += a * w3.y; a3.z += a * w3.z; a3.w += a * w3.w;
        }
        int n = node0 + nl;
        int bb = batch[n];
        const float4* iv = ((const float4*)inj) + bb * 8 + hf * 4;
        float4 i0 = iv[0], i1 = iv[1], i2 = iv[2], i3 = iv[3];
        float4 o0, o1, o2, o3;
        o0.x = i0.x + 0.2f*a0.x; o0.y = i0.y + 0.2f*a0.y;
        o0.z = i0.z + 0.2f*a0.z; o0.w = i0.w + 0.2f*a0.w;
        o1.x = i1.x + 0.2f*a1.x; o1.y = i1.y + 0.2f*a1.y;
        o1.z = i1.z + 0.2f*a1.z; o1.w = i1.w + 0.2f*a1.w;
        o2.x = i2.x + 0.2f*a2.x; o2.y = i2.y + 0.2f*a2.y;
        o2.z = i2.z + 0.2f*a2.z; o2.w = i2.w + 0.2f*a2.w;
        o3.x = i3.x + 0.2f*a3.x; o3.y = i3.y + 0.2f*a3.y;
        o3.z = i3.z + 0.2f*a3.z; o3.w = i3.w + 0.2f*a3.w;
        float4* op = ((float4*)out) + (size_t)n * 8 + hf * 4;
        op[0] = o0; op[1] = o1; op[2] = o2; op[3] = o3;
    }
}

// ---- fallback: fused temb + init + direct atomic scatter ------------------
__global__ __launch_bounds__(256) void temb_fused_kernel(
    const float* __restrict__ t,
    const float* __restrict__ W1, const float* __restrict__ b1,
    const float* __restrict__ W2, const float* __restrict__ b2,
    const float* __restrict__ Wt, float* __restrict__ inj)
{
    int b = blockIdx.x;
    int tid = threadIdx.x;
    __shared__ float emb[128];
    __shared__ float s1[512];
    __shared__ float s2[512];
    __shared__ float red[256];
    float tv = t[b];
    if (tid < 128) {
        const float kStep = 9.210340371976184f / 63.0f;
        int k = tid & 63;
        float ang = tv * expf(-(float)k * kStep);
        emb[tid] = (tid < 64) ? sinf(ang) : cosf(ang);
    }
    __syncthreads();
    {
        float a0 = 0.f, a1 = 0.f;
        for (int k = 0; k < 128; ++k) {
            float e = emb[k];
            a0 += e * W1[k * 512 + tid];
            a1 += e * W1[k * 512 + tid + 256];
        }
        float v0 = a0 + b1[tid], v1 = a1 + b1[tid + 256];
        s1[tid]       = v0 / (1.0f + expf(-v0));
        s1[tid + 256] = v1 / (1.0f + expf(-v1));
    }
    __syncthreads();
    {
        float a0 = 0.f, a1 = 0.f;
        for (int k = 0; k < 512; ++k) {
            float e = s1[k];
            a0 += e * W2[k * 512 + tid];
            a1 += e * W2[k * 512 + tid + 256];
        }
        float v0 = a0 + b2[tid], v1 = a1 + b2[tid + 256];
        s2[tid]       = v0 / (1.0f + expf(-v0));
        s2[tid + 256] = v1 / (1.0f + expf(-v1));
    }
    __syncthreads();
    {
        int c = tid & 31, seg = tid >> 5;
        float acc = 0.f;
        int k0 = seg * 64;
        for (int k = k0; k < k0 + 64; ++k)
            acc += s2[k] * Wt[k * 32 + c];
        red[tid] = acc;
        __syncthreads();
        if (tid < 32) {
            float s = 0.f;
#pragma unroll
            for (int g = 0; g < 8; ++g) s += red[g * 32 + tid];
            inj[b * 32 + tid] = s;
        }
    }
}

__global__ __launch_bounds__(256) void init_kernel(
    const int* __restrict__ batch_id, const float* __restrict__ inj,
    float4* __restrict__ out, int N)
{
    int gid = blockIdx.x * 256 + threadIdx.x;
    if (gid >= N * 8) return;
    int n = gid >> 3, q = gid & 7;
    int b = batch_id[n];
    out[gid] = ((const float4*)inj)[b * 8 + q];
}

__global__ __launch_bounds__(256) void edge_direct_kernel(
    const int* __restrict__ ei, const int* __restrict__ etype,
    const int* __restrict__ ntype, const float* __restrict__ x,
    const float* __restrict__ Wc, float* __restrict__ out, int E)
{
    __shared__ float Ws[55 * 32];
    for (int i = threadIdx.x; i < 55 * 32; i += 256) Ws[i] = Wc[i];
    __syncthreads();
    unsigned total = (unsigned)E * 32u;
    unsigned stride = gridDim.x * 256u;
    for (unsigned idx = blockIdx.x * 256u + threadIdx.x; idx < total;
         idx += stride) {
        int e = (int)(idx >> 5);
        int c = (int)(idx & 31);
        int row = ei[e];
        int col = ei[E + e];
        int T = etype[e];
        int nt = ntype[col];
        float4 xv = ((const float4*)x)[col];
        const float* wb = Ws + T * 352;
        float y = xv.x * wb[c] + xv.y * wb[32 + c] + xv.z * wb[64 + c] +
                  xv.w * wb[96 + c] + wb[(4 + nt) * 32 + c];
        atomicAdd(out + (size_t)row * 32 + c, y * 0.2f);
    }
}

extern "C" void kernel_launch(void* const* d_in, const int* in_sizes, int n_in,
                              void* d_out, int out_size, void* d_ws, size_t ws_size,
                              hipStream_t stream) {
    const float* x     = (const float*)d_in[0];   // [N,4]
    const float* t     = (const float*)d_in[1];   // [8]
    const int*   ei    = (const int*)d_in[2];     // [2,E]
    const int*   etype = (const int*)d_in[3];     // [E]
    const int*   ntype = (const int*)d_in[4];     // [N]
    const int*   batch = (const int*)d_in[5];     // [N]
    const float* Wc    = (const float*)d_in[6];   // [55,32]
    const float* W1    = (const float*)d_in[7];   // [128,512]
    const float* b1    = (const float*)d_in[8];   // [512]
    const float* W2    = (const float*)d_in[9];   // [512,512]
    const float* b2    = (const float*)d_in[10];  // [512]
    const float* Wt    = (const float*)d_in[11];  // [512,32]
    float* out = (float*)d_out;

    int E = in_sizes[3];
    int N = in_sizes[4];

    int NBC = (N + CW - 1) >> CWSH;               // coarse buckets
    int NFp = NBC * NW;                           // padded fine buckets
    int NFr = (N + WSZ - 1) >> WSH;               // real fine buckets
    int NCH = (E + CH - 1) / CH;
    int NCHP = 1, LOGC = 0;
    while (NCHP < NCH) { NCHP <<= 1; ++LOGC; }
    size_t M = (size_t)NBC << LOGC;
    int nblkA = (int)((M + 4095) / 4096);

    // ws layout (4-byte units)
    float* ws     = (float*)d_ws;
    float* h1acc  = ws;                           // 4096
    float* h2acc  = ws + 4096;                    // 4096
    float* inj    = ws + 8192;                    // 256
    int*   fineRep = (int*)(ws + 8448);           // 8*NFp
    int*   counts = fineRep + (size_t)8 * NFp;    // M
    int*   base   = counts + M;                   // M
    int*   bsums  = base + M;                     // 1024
    int*   bstart = bsums + 1024;                 // NBC+1
    int*   fineSt = bstart + NBC + 1;             // NFp+1
    size_t recOff = 8448 + (size_t)8 * NFp + 2 * M + 1024 + (NBC + 1) + (NFp + 1);
    recOff = (recOff + 1) & ~(size_t)1;           // 8B align
    uint2*    rec  = (uint2*)(ws + recOff);       // 2E words
    unsigned* rec2 = (unsigned*)(ws + recOff + 2 * (size_t)E);  // E words

    size_t needBytes = (recOff + 3 * (size_t)E) * 4;
    bool okay = (NBC <= NBCMAX) && (NFp <= NFPMAX) && (nblkA <= 1024) &&
                (ws_size >= needBytes) && (N <= 524288) &&
                (M < (size_t)1 << 30);

    if (okay) {
        hipMemsetAsync(fineRep, 0, (size_t)8 * NFp * 4, stream);

        histW_kernel<<<NCHP + 8, 256, 0, stream>>>(
            ei, counts, fineRep, t, W1, h1acc, h2acc, inj, E, NBC, NFp, NCHP);
        scanA_kernel<<<nblkA + 64, 256, 0, stream>>>(
            counts, bsums, h1acc, b1, W2, h2acc, (int)M, NBC, LOGC, nblkA);
        scanBF_kernel<<<1, 1024, 0, stream>>>(
            bsums, bstart, fineRep, fineSt, nblkA, NBC, NFp, E);
        scanC_kernel<<<nblkA + 8, 256, 0, stream>>>(
            counts, bsums, base, bstart, h2acc, b2, Wt, inj,
            (int)M, NBC, LOGC, nblkA);
        scatter_kernel<<<NCH, 512, 0, stream>>>(
            ei, etype, ntype, base, rec, E, NBC, LOGC);
        repack_kernel<<<NBC, 1024, 0, stream>>>(bstart, fineSt, rec, rec2);
        consume_kernel<<<NFr, 256, 0, stream>>>(
            fineSt, rec2, x, Wc, batch, inj, out, N);
    } else {
        temb_fused_kernel<<<8, 256, 0, stream>>>(t, W1, b1, W2, b2, Wt, inj);
        init_kernel<<<(N * 8 + 255) / 256, 256, 0, stream>>>(
            batch, inj, (float4*)out, N);
        edge_direct_kernel<<<16384, 256, 0, stream>>>(
            ei, etype, ntype, x, Wc, out, E);
    }
}

// Round 9
// 251.580 us; speedup vs baseline: 1.5090x; 1.0395x over previous
//
#include <hip/hip_runtime.h>
#include <hip/hip_fp16.h>

// ---------------------------------------------------------------------------
// N=400000, E=2000000, B=8, C_IN=4, N_EDGE_TYPE=5, N_NODE_TYPE=7, C_OUT=32.
//
// HW model (measured, rounds 0-8):
//  - Global atomics into 88MB fp32 thrash L2: 504us (R1). DEAD END.
//  - Write-merge RULE: multi-XCD sub-line writes amplify (R3). Coarse
//    (>=64B) regions merge fine (R7/R8 scatter).
//  - consume epilogue fixed in R8 (wave-uniform Wc -> SMEM): 101->80us.
//    Residue: x-gather line traffic (FETCH 70MB; x=6.4MB > 4MB/XCD L2).
//  - Front-end 181us vs ~15us of streaming traffic: scalar edge loads,
//    under-occupied scatter.
//  => R9: (1) x -> fp16 half4 (3.2MB, L2-resident) converted in histW;
//     (2) consume 512thr (4 blk/CU = 32 waves, full occupancy);
//     (3) int4 edge loads in histW + scatter.
// ---------------------------------------------------------------------------

#define CH      4096       // edges per chunk
#define CW      2048       // coarse bucket width (nodes)
#define CWSH    11         // log2(CW)
#define WSZ     128        // fine bucket / consume window (nodes)
#define WSH     7          // log2(WSZ)
#define NW      16         // fine per coarse = CW/WSZ
#define NBCMAX  512        // max coarse buckets
#define NFPMAX  8192       // max padded fine buckets (LDS hist)

__device__ __forceinline__ unsigned pack2(float a, float b) {
    __half2 h = __floats2half2_rn(a, b);
    union { __half2 h; unsigned u; } cv; cv.h = h; return cv.u;
}
__device__ __forceinline__ float2 unpack2(unsigned u) {
    union { unsigned u; __half2 h; } cv; cv.u = u;
    return __half22float2(cv.h);
}

// ---- histW: chunk blocks: fine LDS hist (int4 loads) + coarse row +
// ---- replica merge + x->fp16 slice. extra 8 blocks: temb stage1 ----------
__global__ __launch_bounds__(256) void histW_kernel(
    const int* __restrict__ ei, int* __restrict__ counts,
    int* __restrict__ fineRep, const float* __restrict__ x,
    uint2* __restrict__ xh,
    const float* __restrict__ t, const float* __restrict__ W1,
    float* __restrict__ h1acc, float* __restrict__ h2acc,
    float* __restrict__ inj,
    int E, int N, int NBC, int NFp, int NCHP)
{
    int tid = threadIdx.x;
    if ((int)blockIdx.x >= NCHP) {
        int b = blockIdx.x - NCHP;
        __shared__ float emb[128];
        if (tid < 128) {
            const float kStep = 9.210340371976184f / 63.0f;
            int k = tid & 63;
            float ang = t[b] * expf(-(float)k * kStep);
            emb[tid] = (tid < 64) ? sinf(ang) : cosf(ang);
        }
        __syncthreads();
        for (int j = tid; j < 512; j += 256) {
            float a = 0.f;
            for (int k = 0; k < 128; ++k) a += emb[k] * W1[k * 512 + j];
            h1acc[b * 512 + j] = a;        // pre-bias/swish
            h2acc[b * 512 + j] = 0.f;
        }
        if (tid < 32) inj[b * 32 + tid] = 0.f;
        return;
    }
    __shared__ int fh[NFPMAX];
    int c = blockIdx.x;
    for (int i = tid; i < NFp; i += 256) fh[i] = 0;
    __syncthreads();
    int s = c * CH, e = min(s + CH, E);
    int nfull = (e - s) & ~3;
    for (int i0 = s + tid * 4; i0 < s + nfull; i0 += 1024) {
        int4 r4 = *(const int4*)&ei[i0];
        atomicAdd(&fh[r4.x >> WSH], 1);
        atomicAdd(&fh[r4.y >> WSH], 1);
        atomicAdd(&fh[r4.z >> WSH], 1);
        atomicAdd(&fh[r4.w >> WSH], 1);
    }
    for (int i = s + nfull + tid; i < e; i += 256)
        atomicAdd(&fh[ei[i] >> WSH], 1);
    __syncthreads();
    int* row = counts + (size_t)c * NBC;
    for (int b = tid; b < NBC; b += 256) {
        int sum = 0;
#pragma unroll
        for (int w = 0; w < NW; ++w) sum += fh[b * NW + w];
        row[b] = sum;
    }
    int* rep = fineRep + (size_t)(blockIdx.x & 7) * NFp;
    for (int i = tid; i < NFp; i += 256) {
        int v = fh[i];
        if (v) atomicAdd(&rep[i], v);
    }
    // x -> fp16 slice (independent of hist)
    int per = (N + NCHP - 1) / NCHP;
    int n0 = c * per, n1 = min(n0 + per, N);
    for (int n = n0 + tid; n < n1; n += 256) {
        float4 v = ((const float4*)x)[n];
        uint2 p;
        p.x = pack2(v.x, v.y);
        p.y = pack2(v.z, v.w);
        xh[n] = p;
    }
}

// ---- scanA: per-block sums (j=(b<<LOGC)+c); extra 64 blocks = temb stage2 -
__global__ __launch_bounds__(256) void scanA_kernel(
    const int* __restrict__ counts, int* __restrict__ bsums,
    const float* __restrict__ h1acc, const float* __restrict__ b1,
    const float* __restrict__ W2, float* __restrict__ h2acc,
    int M, int NBC, int LOGC, int nblkA)
{
    int tid = threadIdx.x;
    if ((int)blockIdx.x >= nblkA) {
        int p = blockIdx.x - nblkA;            // k-slice [8p, 8p+8)
        __shared__ float h1s[64];              // [b*8+kk]
        if (tid < 64) {
            int bb = tid >> 3, kk = tid & 7;
            int k = p * 8 + kk;
            float v = h1acc[bb * 512 + k] + b1[k];
            h1s[tid] = v / (1.f + expf(-v));
        }
        __syncthreads();
        for (int jj = 0; jj < 2; ++jj) {
            int j = tid + jj * 256;
            float acc[8] = {};
#pragma unroll
            for (int kk = 0; kk < 8; ++kk) {
                float w = W2[(p * 8 + kk) * 512 + j];
#pragma unroll
                for (int bb = 0; bb < 8; ++bb) acc[bb] += h1s[bb * 8 + kk] * w;
            }
#pragma unroll
            for (int bb = 0; bb < 8; ++bb)
                atomicAdd(&h2acc[bb * 512 + j], acc[bb]);
        }
        return;
    }
    __shared__ int s[256];
    int j0 = blockIdx.x * 4096 + tid * 16;
    int maskC = (1 << LOGC) - 1;
    int p = 0;
#pragma unroll
    for (int k = 0; k < 16; ++k) {
        int j = j0 + k;
        if (j < M) {
            int b = j >> LOGC, c = j & maskC;
            p += counts[(size_t)c * NBC + b];
        }
    }
    s[tid] = p; __syncthreads();
    for (int off = 128; off > 0; off >>= 1) {
        if (tid < off) s[tid] += s[tid + off];
        __syncthreads();
    }
    if (tid == 0) bsums[blockIdx.x] = s[0];
}

// ---- scanBF: 1 block: coarse block-sum scan + fine exclusive scan ---------
__global__ __launch_bounds__(1024) void scanBF_kernel(
    int* __restrict__ bsums, int* __restrict__ bstart,
    const int* __restrict__ fineRep, int* __restrict__ fineStart,
    int nblk, int NBC, int NFp, int E)
{
    __shared__ int s[1024];
    __shared__ int fs[1024];
    int tid = threadIdx.x;
    int v = (tid < nblk) ? bsums[tid] : 0;
    s[tid] = v; __syncthreads();
    for (int off = 1; off < 1024; off <<= 1) {
        int u = (tid >= off) ? s[tid - off] : 0;
        __syncthreads();
        s[tid] += u;
        __syncthreads();
    }
    if (tid < nblk) bsums[tid] = s[tid] - v;          // exclusive
    if (tid == 0) bstart[NBC] = E;
    // ---- fine scan ----
    int PTF = (NFp + 1023) >> 10;
    int b0 = tid * PTF;
    int run = 0;
    for (int q = 0; q < PTF; ++q) {
        int i = b0 + q;
        if (i < NFp) {
            int csum = 0;
#pragma unroll
            for (int r = 0; r < 8; ++r) csum += fineRep[(size_t)r * NFp + i];
            run += csum;
        }
    }
    fs[tid] = run; __syncthreads();
    for (int off = 1; off < 1024; off <<= 1) {
        int u = (tid >= off) ? fs[tid - off] : 0;
        __syncthreads();
        fs[tid] += u;
        __syncthreads();
    }
    int tbase = fs[tid] - run;
    for (int q = 0; q < PTF; ++q) {
        int i = b0 + q;
        if (i < NFp) {
            int csum = 0;
#pragma unroll
            for (int r = 0; r < 8; ++r) csum += fineRep[(size_t)r * NFp + i];
            fineStart[i] = tbase;
            tbase += csum;
        }
    }
    if (tid == 0) fineStart[NFp] = E;
}

// ---- scanC: per-(bucket,chunk) bases + bstart; extra 8 blocks = stage3 ----
__global__ __launch_bounds__(256) void scanC_kernel(
    const int* __restrict__ counts, const int* __restrict__ bsums,
    int* __restrict__ base, int* __restrict__ bstart,
    const float* __restrict__ h2acc, const float* __restrict__ b2,
    const float* __restrict__ Wt, float* __restrict__ inj,
    int M, int NBC, int LOGC, int nblkA)
{
    int tid = threadIdx.x;
    if ((int)blockIdx.x >= nblkA) {
        int ks = blockIdx.x - nblkA;
        __shared__ float sws[8][64];
        for (int i = tid; i < 512; i += 256) {
            int b = i >> 6, kk = i & 63;
            int k = ks * 64 + kk;
            float v = h2acc[b * 512 + k] + b2[k];
            sws[b][kk] = v / (1.f + expf(-v));
        }
        __syncthreads();
        int b = tid >> 5, c = tid & 31;
        float acc = 0.f;
        for (int kk = 0; kk < 64; ++kk)
            acc += sws[b][kk] * Wt[(ks * 64 + kk) * 32 + c];
        atomicAdd(&inj[tid], acc);
        return;
    }
    __shared__ int s[256];
    int j0 = blockIdx.x * 4096 + tid * 16;
    int maskC = (1 << LOGC) - 1;
    int v[16]; int p = 0;
#pragma unroll
    for (int k = 0; k < 16; ++k) {
        int j = j0 + k;
        v[k] = 0;
        if (j < M) {
            int b = j >> LOGC, c = j & maskC;
            v[k] = counts[(size_t)c * NBC + b];
        }
        p += v[k];
    }
    s[tid] = p; __syncthreads();
    for (int off = 1; off < 256; off <<= 1) {
        int u = (tid >= off) ? s[tid - off] : 0;
        __syncthreads();
        s[tid] += u;
        __syncthreads();
    }
    int run = bsums[blockIdx.x] + (s[tid] - p);
#pragma unroll
    for (int k = 0; k < 16; ++k) {
        int j = j0 + k;
        if (j < M) {
            base[j] = run;
            if ((j & maskC) == 0) bstart[j >> LOGC] = run;
            run += v[k];
        }
    }
}

// ---- scatter: block per chunk; XCD swizzle; int4 loads; 8B recs -----------
// rec = { col | T<<19 | nt<<22 , row & (CW-1) }
__global__ __launch_bounds__(512) void scatter_kernel(
    const int* __restrict__ ei, const int* __restrict__ etype,
    const int* __restrict__ ntype, const int* __restrict__ base,
    uint2* __restrict__ rec, int E, int NBC, int LOGC)
{
    __shared__ int cur[NBCMAX];
    int tid = threadIdx.x;
    int nwg = gridDim.x;
    int q = nwg >> 3, r = nwg & 7;
    int xcd = blockIdx.x & 7, idx = blockIdx.x >> 3;
    int c = (xcd < r) ? xcd * (q + 1) + idx
                      : r * (q + 1) + (xcd - r) * q + idx;
    for (int b = tid; b < NBC; b += 512)
        cur[b] = base[((size_t)b << LOGC) + c];
    __syncthreads();
    int s = c * CH, e = min(s + CH, E);
    int nfull = (e - s) & ~3;
    for (int i0 = s + tid * 4; i0 < s + nfull; i0 += 2048) {
        int4 r4 = *(const int4*)&ei[i0];
        int4 c4 = *(const int4*)&ei[E + i0];
        int4 t4 = *(const int4*)&etype[i0];
#pragma unroll
        for (int k = 0; k < 4; ++k) {
            int row = (&r4.x)[k], col = (&c4.x)[k], T = (&t4.x)[k];
            int nt = ntype[col];
            int b = row >> CWSH;
            int slot = atomicAdd(&cur[b], 1);
            uint2 rc;
            rc.x = (unsigned)col | ((unsigned)T << 19) | ((unsigned)nt << 22);
            rc.y = (unsigned)(row & (CW - 1));
            rec[slot] = rc;
        }
    }
    for (int i = s + nfull + tid; i < e; i += 512) {
        int row = ei[i], col = ei[E + i];
        int T = etype[i], nt = ntype[col];
        int b = row >> CWSH;
        int slot = atomicAdd(&cur[b], 1);
        uint2 rc;
        rc.x = (unsigned)col | ((unsigned)T << 19) | ((unsigned)nt << 22);
        rc.y = (unsigned)(row & (CW - 1));
        rec[slot] = rc;
    }
}

// ---- repack: block per coarse bucket; single pass -> 4B fine-sorted recs --
__global__ __launch_bounds__(1024) void repack_kernel(
    const int* __restrict__ bstart, const int* __restrict__ fineStart,
    const uint2* __restrict__ rec, unsigned* __restrict__ rec2)
{
    __shared__ int cur[NW];
    int tid = threadIdx.x;
    int b = blockIdx.x;
    if (tid < NW) cur[tid] = fineStart[b * NW + tid];
    __syncthreads();
    int s = bstart[b], e = bstart[b + 1];
    for (int i = s + tid; i < e; i += 1024) {
        uint2 rc = rec[i];
        int w = (int)(rc.y >> WSH);
        int slot = atomicAdd(&cur[w], 1);
        rec2[slot] = rc.x | ((rc.y & (WSZ - 1)) << 25);
    }
}

// ---- consume: 512thr block per fine bucket; fp16-L2 gather; 8ch epilogue --
__global__ __launch_bounds__(512) void consume_kernel(
    const int* __restrict__ fineStart, const unsigned* __restrict__ rec2,
    const uint2* __restrict__ xh, const float* __restrict__ Wc,
    const int* __restrict__ batch, const float* __restrict__ inj,
    float* __restrict__ out, int N)
{
    __shared__ __align__(16) float tile[WSZ * 57];  // 29184 B
    int tid = threadIdx.x;
    int f = blockIdx.x;
    int node0 = f << WSH;

    for (int i = tid; i < WSZ * 57 / 4; i += 512)
        ((float4*)tile)[i] = make_float4(0.f, 0.f, 0.f, 0.f);
    __syncthreads();

    int s = fineStart[f], e = fineStart[f + 1];
    for (int i = s + tid; i < e; i += 512) {
        unsigned u = rec2[i];
        int col  = (int)(u & 0x7FFFFu);
        int T    = (int)((u >> 19) & 7u);
        int nt   = (int)((u >> 22) & 7u);
        int lrow = (int)(u >> 25);
        uint2 p = xh[col];
        float2 f01 = unpack2(p.x);
        float2 f23 = unpack2(p.y);
        float* tr = tile + lrow * 57 + T * 11;
        atomicAdd(tr + 0, f01.x);
        atomicAdd(tr + 1, f01.y);
        atomicAdd(tr + 2, f23.x);
        atomicAdd(tr + 3, f23.y);
        atomicAdd(tr + 4 + nt, 1.0f);
    }
    __syncthreads();

    int nodes = N - node0; if (nodes > WSZ) nodes = WSZ;
    int nl = tid & (WSZ - 1);
    int hf = __builtin_amdgcn_readfirstlane((int)tid >> 7);  // 0..3, wave-uniform
    if (nl < nodes) {
        const float* ar = tile + nl * 57;
        const float4* wq = (const float4*)Wc;
        float4 a0 = {0.f,0.f,0.f,0.f}, a1 = a0;
#pragma unroll 5
        for (int k = 0; k < 55; ++k) {
            float a = ar[k];
            float4 w0 = wq[k * 8 + hf * 2];
            float4 w1 = wq[k * 8 + hf * 2 + 1];
            a0.x += a * w0.x; a0.y += a * w0.y; a0.z += a * w0.z; a0.w += a * w0.w;
            a1.x += a * w1.x; a1.y += a * w1.y; a1.z += a * w1.z; a1.w += a * w1.w;
        }
        int n = node0 + nl;
        int bb = batch[n];
        const float4* iv = ((const float4*)inj) + bb * 8 + hf * 2;
        float4 i0 = iv[0], i1 = iv[1];
        float4 o0, o1;
        o0.x = i0.x + 0.2f*a0.x; o0.y = i0.y + 0.2f*a0.y;
        o0.z = i0.z + 0.2f*a0.z; o0.w = i0.w + 0.2f*a0.w;
        o1.x = i1.x + 0.2f*a1.x; o1.y = i1.y + 0.2f*a1.y;
        o1.z = i1.z + 0.2f*a1.z; o1.w = i1.w + 0.2f*a1.w;
        float4* op = ((float4*)out) + (size_t)n * 8 + hf * 2;
        op[0] = o0; op[1] = o1;
    }
}

// ---- fallback: fused temb + init + direct atomic scatter ------------------
__global__ __launch_bounds__(256) void temb_fused_kernel(
    const float* __restrict__ t,
    const float* __restrict__ W1, const float* __restrict__ b1,
    const float* __restrict__ W2, const float* __restrict__ b2,
    const float* __restrict__ Wt, float* __restrict__ inj)
{
    int b = blockIdx.x;
    int tid = threadIdx.x;
    __shared__ float emb[128];
    __shared__ float s1[512];
    __shared__ float s2[512];
    __shared__ float red[256];
    float tv = t[b];
    if (tid < 128) {
        const float kStep = 9.210340371976184f / 63.0f;
        int k = tid & 63;
        float ang = tv * expf(-(float)k * kStep);
        emb[tid] = (tid < 64) ? sinf(ang) : cosf(ang);
    }
    __syncthreads();
    {
        float a0 = 0.f, a1 = 0.f;
        for (int k = 0; k < 128; ++k) {
            float e = emb[k];
            a0 += e * W1[k * 512 + tid];
            a1 += e * W1[k * 512 + tid + 256];
        }
        float v0 = a0 + b1[tid], v1 = a1 + b1[tid + 256];
        s1[tid]       = v0 / (1.0f + expf(-v0));
        s1[tid + 256] = v1 / (1.0f + expf(-v1));
    }
    __syncthreads();
    {
        float a0 = 0.f, a1 = 0.f;
        for (int k = 0; k < 512; ++k) {
            float e = s1[k];
            a0 += e * W2[k * 512 + tid];
            a1 += e * W2[k * 512 + tid + 256];
        }
        float v0 = a0 + b2[tid], v1 = a1 + b2[tid + 256];
        s2[tid]       = v0 / (1.0f + expf(-v0));
        s2[tid + 256] = v1 / (1.0f + expf(-v1));
    }
    __syncthreads();
    {
        int c = tid & 31, seg = tid >> 5;
        float acc = 0.f;
        int k0 = seg * 64;
        for (int k = k0; k < k0 + 64; ++k)
            acc += s2[k] * Wt[k * 32 + c];
        red[tid] = acc;
        __syncthreads();
        if (tid < 32) {
            float s = 0.f;
#pragma unroll
            for (int g = 0; g < 8; ++g) s += red[g * 32 + tid];
            inj[b * 32 + tid] = s;
        }
    }
}

__global__ __launch_bounds__(256) void init_kernel(
    const int* __restrict__ batch_id, const float* __restrict__ inj,
    float4* __restrict__ out, int N)
{
    int gid = blockIdx.x * 256 + threadIdx.x;
    if (gid >= N * 8) return;
    int n = gid >> 3, q = gid & 7;
    int b = batch_id[n];
    out[gid] = ((const float4*)inj)[b * 8 + q];
}

__global__ __launch_bounds__(256) void edge_direct_kernel(
    const int* __restrict__ ei, const int* __restrict__ etype,
    const int* __restrict__ ntype, const float* __restrict__ x,
    const float* __restrict__ Wc, float* __restrict__ out, int E)
{
    __shared__ float Ws[55 * 32];
    for (int i = threadIdx.x; i < 55 * 32; i += 256) Ws[i] = Wc[i];
    __syncthreads();
    unsigned total = (unsigned)E * 32u;
    unsigned stride = gridDim.x * 256u;
    for (unsigned idx = blockIdx.x * 256u + threadIdx.x; idx < total;
         idx += stride) {
        int e = (int)(idx >> 5);
        int c = (int)(idx & 31);
        int row = ei[e];
        int col = ei[E + e];
        int T = etype[e];
        int nt = ntype[col];
        float4 xv = ((const float4*)x)[col];
        const float* wb = Ws + T * 352;
        float y = xv.x * wb[c] + xv.y * wb[32 + c] + xv.z * wb[64 + c] +
                  xv.w * wb[96 + c] + wb[(4 + nt) * 32 + c];
        atomicAdd(out + (size_t)row * 32 + c, y * 0.2f);
    }
}

extern "C" void kernel_launch(void* const* d_in, const int* in_sizes, int n_in,
                              void* d_out, int out_size, void* d_ws, size_t ws_size,
                              hipStream_t stream) {
    const float* x     = (const float*)d_in[0];   // [N,4]
    const float* t     = (const float*)d_in[1];   // [8]
    const int*   ei    = (const int*)d_in[2];     // [2,E]
    const int*   etype = (const int*)d_in[3];     // [E]
    const int*   ntype = (const int*)d_in[4];     // [N]
    const int*   batch = (const int*)d_in[5];     // [N]
    const float* Wc    = (const float*)d_in[6];   // [55,32]
    const float* W1    = (const float*)d_in[7];   // [128,512]
    const float* b1    = (const float*)d_in[8];   // [512]
    const float* W2    = (const float*)d_in[9];   // [512,512]
    const float* b2    = (const float*)d_in[10];  // [512]
    const float* Wt    = (const float*)d_in[11];  // [512,32]
    float* out = (float*)d_out;

    int E = in_sizes[3];
    int N = in_sizes[4];

    int NBC = (N + CW - 1) >> CWSH;               // coarse buckets
    int NFp = NBC * NW;                           // padded fine buckets
    int NFr = (N + WSZ - 1) >> WSH;               // real fine buckets
    int NCH = (E + CH - 1) / CH;
    int NCHP = 1, LOGC = 0;
    while (NCHP < NCH) { NCHP <<= 1; ++LOGC; }
    size_t M = (size_t)NBC << LOGC;
    int nblkA = (int)((M + 4095) / 4096);

    // ws layout (4-byte units)
    float* ws     = (float*)d_ws;
    float* h1acc  = ws;                           // 4096
    float* h2acc  = ws + 4096;                    // 4096
    float* inj    = ws + 8192;                    // 256
    uint2* xh     = (uint2*)(ws + 8448);          // 2N words (8B/node)
    int*   fineRep = (int*)(ws + 8448 + 2 * (size_t)N);  // 8*NFp
    int*   counts = fineRep + (size_t)8 * NFp;    // M
    int*   base   = counts + M;                   // M
    int*   bsums  = base + M;                     // 1024
    int*   bstart = bsums + 1024;                 // NBC+1
    int*   fineSt = bstart + NBC + 1;             // NFp+1
    size_t recOff = 8448 + 2 * (size_t)N + (size_t)8 * NFp + 2 * M + 1024 +
                    (NBC + 1) + (NFp + 1);
    recOff = (recOff + 1) & ~(size_t)1;           // 8B align
    uint2*    rec  = (uint2*)(ws + recOff);       // 2E words
    unsigned* rec2 = (unsigned*)(ws + recOff + 2 * (size_t)E);  // E words

    size_t needBytes = (recOff + 3 * (size_t)E) * 4;
    bool okay = (NBC <= NBCMAX) && (NFp <= NFPMAX) && (nblkA <= 1024) &&
                (ws_size >= needBytes) && (N <= 524288) &&
                ((E & 3) == 0) && (M < (size_t)1 << 30);

    if (okay) {
        hipMemsetAsync(fineRep, 0, (size_t)8 * NFp * 4, stream);

        histW_kernel<<<NCHP + 8, 256, 0, stream>>>(
            ei, counts, fineRep, x, xh, t, W1, h1acc, h2acc, inj,
            E, N, NBC, NFp, NCHP);
        scanA_kernel<<<nblkA + 64, 256, 0, stream>>>(
            counts, bsums, h1acc, b1, W2, h2acc, (int)M, NBC, LOGC, nblkA);
        scanBF_kernel<<<1, 1024, 0, stream>>>(
            bsums, bstart, fineRep, fineSt, nblkA, NBC, NFp, E);
        scanC_kernel<<<nblkA + 8, 256, 0, stream>>>(
            counts, bsums, base, bstart, h2acc, b2, Wt, inj,
            (int)M, NBC, LOGC, nblkA);
        scatter_kernel<<<NCH, 512, 0, stream>>>(
            ei, etype, ntype, base, rec, E, NBC, LOGC);
        repack_kernel<<<NBC, 1024, 0, stream>>>(bstart, fineSt, rec, rec2);
        consume_kernel<<<NFr, 512, 0, stream>>>(
            fineSt, rec2, xh, Wc, batch, inj, out, N);
    } else {
        temb_fused_kernel<<<8, 256, 0, stream>>>(t, W1, b1, W2, b2, Wt, inj);
        init_kernel<<<(N * 8 + 255) / 256, 256, 0, stream>>>(
            batch, inj, (float4*)out, N);
        edge_direct_kernel<<<16384, 256, 0, stream>>>(
            ei, etype, ntype, x, Wc, out, E);
    }
}

// Round 10
// 222.086 us; speedup vs baseline: 1.7094x; 1.1328x over previous
//
#include <hip/hip_runtime.h>
#include <hip/hip_fp16.h>

// ---------------------------------------------------------------------------
// N=400000, E=2000000, B=8, C_IN=4, N_EDGE_TYPE=5, N_NODE_TYPE=7, C_OUT=32.
//
// HW model (measured, rounds 0-9):
//  - Global atomics into 88MB fp32 thrash L2: 504us (R1). DEAD END.
//  - Write-merge RULE: multi-XCD sub-line writes amplify (R3); coarse
//    (>=64B) regions merge fine.
//  - consume has an ~80us floor INVARIANT to fetch (70->33MB), gathers
//    (random fp32 -> L2 fp16 -> none), occupancy (37->68%): R2 105, R7 101,
//    R8 80, R9 79. Common factor: 10M LDS atomics (5/edge). Hypothesis:
//    LDS-atomic RMW throughput bound.
//  => R10: repack sorts to EXACT NODE (2048-ctr hist + scan + cursors,
//     writes nodeStart[N+1] + 4B recs {col|T|nt}); consume stages recs+x
//     with plain LDS stores and accumulates per-node in REGISTERS
//     (predicated-T FMAs + 8-bit packed nt counters) -- zero LDS atomics.
//     Fine-hist/fineRep/memset deleted; 7 dispatches.
// ---------------------------------------------------------------------------

#define CH      4096       // edges per chunk
#define CW      2048       // coarse bucket width (nodes)
#define CWSH    11         // log2(CW)
#define WSZ     128        // consume window (nodes)
#define WSH     7          // log2(WSZ)
#define NBCMAX  512        // max coarse buckets
#define CAP     2048       // consume stage capacity (records)

__device__ __forceinline__ unsigned pack2(float a, float b) {
    __half2 h = __floats2half2_rn(a, b);
    union { __half2 h; unsigned u; } cv; cv.h = h; return cv.u;
}
__device__ __forceinline__ float2 unpack2(unsigned u) {
    union { unsigned u; __half2 h; } cv; cv.u = u;
    return __half22float2(cv.h);
}

// ---- histW: chunk blocks: coarse LDS hist (int4 loads) + x->fp16 slice.
// ---- extra 8 blocks: temb stage1 (h1 = emb@W1; zero h2acc/inj) -----------
__global__ __launch_bounds__(256) void histW_kernel(
    const int* __restrict__ ei, int* __restrict__ counts,
    const float* __restrict__ x, uint2* __restrict__ xh,
    const float* __restrict__ t, const float* __restrict__ W1,
    float* __restrict__ h1acc, float* __restrict__ h2acc,
    float* __restrict__ inj,
    int E, int N, int NBC, int NCHP)
{
    int tid = threadIdx.x;
    if ((int)blockIdx.x >= NCHP) {
        int b = blockIdx.x - NCHP;
        __shared__ float emb[128];
        if (tid < 128) {
            const float kStep = 9.210340371976184f / 63.0f;
            int k = tid & 63;
            float ang = t[b] * expf(-(float)k * kStep);
            emb[tid] = (tid < 64) ? sinf(ang) : cosf(ang);
        }
        __syncthreads();
        for (int j = tid; j < 512; j += 256) {
            float a = 0.f;
            for (int k = 0; k < 128; ++k) a += emb[k] * W1[k * 512 + j];
            h1acc[b * 512 + j] = a;        // pre-bias/swish
            h2acc[b * 512 + j] = 0.f;
        }
        if (tid < 32) inj[b * 32 + tid] = 0.f;
        return;
    }
    __shared__ int h[NBCMAX];
    int c = blockIdx.x;
    for (int i = tid; i < NBC; i += 256) h[i] = 0;
    __syncthreads();
    int s = c * CH, e = min(s + CH, E);
    int nfull = (e - s) & ~3;
    for (int i0 = s + tid * 4; i0 < s + nfull; i0 += 1024) {
        int4 r4 = *(const int4*)&ei[i0];
        atomicAdd(&h[r4.x >> CWSH], 1);
        atomicAdd(&h[r4.y >> CWSH], 1);
        atomicAdd(&h[r4.z >> CWSH], 1);
        atomicAdd(&h[r4.w >> CWSH], 1);
    }
    for (int i = s + nfull + tid; i < e; i += 256)
        atomicAdd(&h[ei[i] >> CWSH], 1);
    __syncthreads();
    int* row = counts + (size_t)c * NBC;
    for (int b = tid; b < NBC; b += 256) row[b] = h[b];
    // x -> fp16 slice (independent of hist)
    int per = (N + NCHP - 1) / NCHP;
    int n0 = c * per, n1 = min(n0 + per, N);
    for (int n = n0 + tid; n < n1; n += 256) {
        float4 v = ((const float4*)x)[n];
        uint2 p;
        p.x = pack2(v.x, v.y);
        p.y = pack2(v.z, v.w);
        xh[n] = p;
    }
}

// ---- scanA: per-block sums (j=(b<<LOGC)+c); extra 64 blocks = temb stage2 -
__global__ __launch_bounds__(256) void scanA_kernel(
    const int* __restrict__ counts, int* __restrict__ bsums,
    const float* __restrict__ h1acc, const float* __restrict__ b1,
    const float* __restrict__ W2, float* __restrict__ h2acc,
    int M, int NBC, int LOGC, int nblkA)
{
    int tid = threadIdx.x;
    if ((int)blockIdx.x >= nblkA) {
        int p = blockIdx.x - nblkA;            // k-slice [8p, 8p+8)
        __shared__ float h1s[64];              // [b*8+kk]
        if (tid < 64) {
            int bb = tid >> 3, kk = tid & 7;
            int k = p * 8 + kk;
            float v = h1acc[bb * 512 + k] + b1[k];
            h1s[tid] = v / (1.f + expf(-v));
        }
        __syncthreads();
        for (int jj = 0; jj < 2; ++jj) {
            int j = tid + jj * 256;
            float acc[8] = {};
#pragma unroll
            for (int kk = 0; kk < 8; ++kk) {
                float w = W2[(p * 8 + kk) * 512 + j];
#pragma unroll
                for (int bb = 0; bb < 8; ++bb) acc[bb] += h1s[bb * 8 + kk] * w;
            }
#pragma unroll
            for (int bb = 0; bb < 8; ++bb)
                atomicAdd(&h2acc[bb * 512 + j], acc[bb]);
        }
        return;
    }
    __shared__ int s[256];
    int j0 = blockIdx.x * 4096 + tid * 16;
    int maskC = (1 << LOGC) - 1;
    int p = 0;
#pragma unroll
    for (int k = 0; k < 16; ++k) {
        int j = j0 + k;
        if (j < M) {
            int b = j >> LOGC, c = j & maskC;
            p += counts[(size_t)c * NBC + b];
        }
    }
    s[tid] = p; __syncthreads();
    for (int off = 128; off > 0; off >>= 1) {
        if (tid < off) s[tid] += s[tid + off];
        __syncthreads();
    }
    if (tid == 0) bsums[blockIdx.x] = s[0];
}

// ---- scanB: exclusive scan of block sums (single block) -------------------
__global__ __launch_bounds__(1024) void scanB_kernel(
    int* __restrict__ bsums, int* __restrict__ bstart, int nblk, int NBC, int E)
{
    __shared__ int s[1024];
    int tid = threadIdx.x;
    int v = (tid < nblk) ? bsums[tid] : 0;
    s[tid] = v; __syncthreads();
    for (int off = 1; off < 1024; off <<= 1) {
        int u = (tid >= off) ? s[tid - off] : 0;
        __syncthreads();
        s[tid] += u;
        __syncthreads();
    }
    if (tid < nblk) bsums[tid] = s[tid] - v;          // exclusive
    if (tid == 0) bstart[NBC] = E;
}

// ---- scanC: per-(bucket,chunk) bases + bstart; extra 8 blocks = stage3 ----
__global__ __launch_bounds__(256) void scanC_kernel(
    const int* __restrict__ counts, const int* __restrict__ bsums,
    int* __restrict__ base, int* __restrict__ bstart,
    const float* __restrict__ h2acc, const float* __restrict__ b2,
    const float* __restrict__ Wt, float* __restrict__ inj,
    int M, int NBC, int LOGC, int nblkA)
{
    int tid = threadIdx.x;
    if ((int)blockIdx.x >= nblkA) {
        int ks = blockIdx.x - nblkA;
        __shared__ float sws[8][64];
        for (int i = tid; i < 512; i += 256) {
            int b = i >> 6, kk = i & 63;
            int k = ks * 64 + kk;
            float v = h2acc[b * 512 + k] + b2[k];
            sws[b][kk] = v / (1.f + expf(-v));
        }
        __syncthreads();
        int b = tid >> 5, c = tid & 31;
        float acc = 0.f;
        for (int kk = 0; kk < 64; ++kk)
            acc += sws[b][kk] * Wt[(ks * 64 + kk) * 32 + c];
        atomicAdd(&inj[tid], acc);
        return;
    }
    __shared__ int s[256];
    int j0 = blockIdx.x * 4096 + tid * 16;
    int maskC = (1 << LOGC) - 1;
    int v[16]; int p = 0;
#pragma unroll
    for (int k = 0; k < 16; ++k) {
        int j = j0 + k;
        v[k] = 0;
        if (j < M) {
            int b = j >> LOGC, c = j & maskC;
            v[k] = counts[(size_t)c * NBC + b];
        }
        p += v[k];
    }
    s[tid] = p; __syncthreads();
    for (int off = 1; off < 256; off <<= 1) {
        int u = (tid >= off) ? s[tid - off] : 0;
        __syncthreads();
        s[tid] += u;
        __syncthreads();
    }
    int run = bsums[blockIdx.x] + (s[tid] - p);
#pragma unroll
    for (int k = 0; k < 16; ++k) {
        int j = j0 + k;
        if (j < M) {
            base[j] = run;
            if ((j & maskC) == 0) bstart[j >> LOGC] = run;
            run += v[k];
        }
    }
}

// ---- scatter: block per chunk; XCD swizzle; int4 loads; 8B recs -----------
// rec = { col | T<<19 | nt<<22 , row & (CW-1) }
__global__ __launch_bounds__(512) void scatter_kernel(
    const int* __restrict__ ei, const int* __restrict__ etype,
    const int* __restrict__ ntype, const int* __restrict__ base,
    uint2* __restrict__ rec, int E, int NBC, int LOGC)
{
    __shared__ int cur[NBCMAX];
    int tid = threadIdx.x;
    int nwg = gridDim.x;
    int q = nwg >> 3, r = nwg & 7;
    int xcd = blockIdx.x & 7, idx = blockIdx.x >> 3;
    int c = (xcd < r) ? xcd * (q + 1) + idx
                      : r * (q + 1) + (xcd - r) * q + idx;
    for (int b = tid; b < NBC; b += 512)
        cur[b] = base[((size_t)b << LOGC) + c];
    __syncthreads();
    int s = c * CH, e = min(s + CH, E);
    int nfull = (e - s) & ~3;
    for (int i0 = s + tid * 4; i0 < s + nfull; i0 += 2048) {
        int4 r4 = *(const int4*)&ei[i0];
        int4 c4 = *(const int4*)&ei[E + i0];
        int4 t4 = *(const int4*)&etype[i0];
#pragma unroll
        for (int k = 0; k < 4; ++k) {
            int row = (&r4.x)[k], col = (&c4.x)[k], T = (&t4.x)[k];
            int nt = ntype[col];
            int b = row >> CWSH;
            int slot = atomicAdd(&cur[b], 1);
            uint2 rc;
            rc.x = (unsigned)col | ((unsigned)T << 19) | ((unsigned)nt << 22);
            rc.y = (unsigned)(row & (CW - 1));
            rec[slot] = rc;
        }
    }
    for (int i = s + nfull + tid; i < e; i += 512) {
        int row = ei[i], col = ei[E + i];
        int T = etype[i], nt = ntype[col];
        int b = row >> CWSH;
        int slot = atomicAdd(&cur[b], 1);
        uint2 rc;
        rc.x = (unsigned)col | ((unsigned)T << 19) | ((unsigned)nt << 22);
        rc.y = (unsigned)(row & (CW - 1));
        rec[slot] = rc;
    }
}

// ---- repack: block per coarse bucket; NODE-level sort; writes nodeStart ---
__global__ __launch_bounds__(1024) void repack_kernel(
    const int* __restrict__ bstart, const uint2* __restrict__ rec,
    unsigned* __restrict__ rec2, int* __restrict__ nodeStart,
    int NBC, int N, int E)
{
    __shared__ int hist[CW];     // per-node counts -> abs starts -> cursors
    __shared__ int sc[1024];
    int tid = threadIdx.x;
    int b = blockIdx.x;
    for (int i = tid; i < CW; i += 1024) hist[i] = 0;
    __syncthreads();
    int s = bstart[b], e = bstart[b + 1];
    for (int i = s + tid; i < e; i += 1024)
        atomicAdd(&hist[rec[i].y], 1);
    __syncthreads();
    // exclusive scan of hist[2048]: 2 elems/thread + Hillis-Steele over 1024
    int a0 = hist[2 * tid], a1 = hist[2 * tid + 1];
    int tsum = a0 + a1;
    sc[tid] = tsum; __syncthreads();
    for (int off = 1; off < 1024; off <<= 1) {
        int u = (tid >= off) ? sc[tid - off] : 0;
        __syncthreads();
        sc[tid] += u;
        __syncthreads();
    }
    int excl = sc[tid] - tsum;
    hist[2 * tid]     = s + excl;           // absolute start
    hist[2 * tid + 1] = s + excl + a0;
    __syncthreads();
    // write nodeStart for this bucket's nodes
    int nbase = b * CW;
    for (int l = tid; l < CW; l += 1024) {
        int n = nbase + l;
        if (n < N) nodeStart[n] = hist[l];
    }
    if (b == NBC - 1 && tid == 0) nodeStart[N] = E;
    __syncthreads();
    // cursor scatter into node order; drop lrow (position encodes it)
    for (int i = s + tid; i < e; i += 1024) {
        uint2 rc = rec[i];
        int slot = atomicAdd(&hist[rc.y], 1);
        rec2[slot] = rc.x;                  // col | T<<19 | nt<<22
    }
}

// ---- consume: 512thr/128 nodes; register accumulate; ZERO LDS atomics -----
__global__ __launch_bounds__(512) void consume_kernel(
    const int* __restrict__ nodeStart, const unsigned* __restrict__ rec2,
    const uint2* __restrict__ xh, const float* __restrict__ Wc,
    const int* __restrict__ batch, const float* __restrict__ inj,
    float* __restrict__ out, int N)
{
    __shared__ int seg[WSZ + 1];
    __shared__ unsigned smeta[CAP];
    __shared__ unsigned sx01[CAP];
    __shared__ unsigned sx23[CAP];
    int tid = threadIdx.x;
    int f = blockIdx.x;
    int node0 = f << WSH;
    int nodes = N - node0; if (nodes > WSZ) nodes = WSZ;

    for (int i = tid; i <= nodes; i += 512) seg[i] = nodeStart[node0 + i];
    __syncthreads();
    int s = seg[0], e = seg[nodes];

    int nl = tid & (WSZ - 1);
    int myS = (nl < nodes) ? seg[nl] : e;
    int myE = (nl < nodes) ? seg[nl + 1] : e;

    float acc[20] = {};                    // [T][0..3] x-sums
    int cnt0[5] = {}, cnt1[5] = {};        // 8-bit packed nt counts (cap 255;
                                           // max multiplicity here ~6)
    for (int base = s; base < e; base += CAP) {
        int w = e - base; if (w > CAP) w = CAP;
        __syncthreads();                   // protect stage reuse
        for (int i = tid; i < w; i += 512) {
            unsigned u = rec2[base + i];
            smeta[i] = u;
            uint2 p = xh[u & 0x7FFFFu];
            sx01[i] = p.x;
            sx23[i] = p.y;
        }
        __syncthreads();
        int lo = myS > base ? myS : base;
        int hi = myE < base + w ? myE : base + w;
        for (int j = lo; j < hi; ++j) {
            int k = j - base;
            unsigned u = smeta[k];
            int T  = (int)((u >> 19) & 7u);
            int nt = (int)((u >> 22) & 7u);
            float2 x01 = unpack2(sx01[k]);
            float2 x23 = unpack2(sx23[k]);
            int lob = (nt < 4) ? (1 << (nt * 8)) : 0;
            int hib = (nt >= 4) ? (1 << ((nt - 4) * 8)) : 0;
#pragma unroll
            for (int tt = 0; tt < 5; ++tt) {
                bool m = (T == tt);
                acc[tt * 4 + 0] += m ? x01.x : 0.f;
                acc[tt * 4 + 1] += m ? x01.y : 0.f;
                acc[tt * 4 + 2] += m ? x23.x : 0.f;
                acc[tt * 4 + 3] += m ? x23.y : 0.f;
                cnt0[tt] += m ? lob : 0;
                cnt1[tt] += m ? hib : 0;
            }
        }
    }

    if (nl < nodes) {
        int hf = __builtin_amdgcn_readfirstlane((int)tid >> 7);  // 0..3
        const float4* wq = (const float4*)Wc;
        float4 o0 = {0.f, 0.f, 0.f, 0.f}, o1 = o0;
#pragma unroll
        for (int f2 = 0; f2 < 55; ++f2) {
            const int tt = f2 / 11, j = f2 % 11;
            float a;
            if (j < 4) a = acc[tt * 4 + j];
            else {
                const int kk = j - 4;
                a = (kk < 4) ? (float)((cnt0[tt] >> (kk * 8)) & 255)
                             : (float)((cnt1[tt] >> ((kk - 4) * 8)) & 255);
            }
            float4 w0 = wq[f2 * 8 + hf * 2];
            float4 w1 = wq[f2 * 8 + hf * 2 + 1];
            o0.x += a * w0.x; o0.y += a * w0.y; o0.z += a * w0.z; o0.w += a * w0.w;
            o1.x += a * w1.x; o1.y += a * w1.y; o1.z += a * w1.z; o1.w += a * w1.w;
        }
        int n = node0 + nl;
        int bb = batch[n];
        const float4* iv = ((const float4*)inj) + bb * 8 + hf * 2;
        float4 i0 = iv[0], i1 = iv[1];
        float4 r0, r1;
        r0.x = i0.x + 0.2f * o0.x; r0.y = i0.y + 0.2f * o0.y;
        r0.z = i0.z + 0.2f * o0.z; r0.w = i0.w + 0.2f * o0.w;
        r1.x = i1.x + 0.2f * o1.x; r1.y = i1.y + 0.2f * o1.y;
        r1.z = i1.z + 0.2f * o1.z; r1.w = i1.w + 0.2f * o1.w;
        float4* op = ((float4*)out) + (size_t)n * 8 + hf * 2;
        op[0] = r0; op[1] = r1;
    }
}

// ---- fallback: fused temb + init + direct atomic scatter ------------------
__global__ __launch_bounds__(256) void temb_fused_kernel(
    const float* __restrict__ t,
    const float* __restrict__ W1, const float* __restrict__ b1,
    const float* __restrict__ W2, const float* __restrict__ b2,
    const float* __restrict__ Wt, float* __restrict__ inj)
{
    int b = blockIdx.x;
    int tid = threadIdx.x;
    __shared__ float emb[128];
    __shared__ float s1[512];
    __shared__ float s2[512];
    __shared__ float red[256];
    float tv = t[b];
    if (tid < 128) {
        const float kStep = 9.210340371976184f / 63.0f;
        int k = tid & 63;
        float ang = tv * expf(-(float)k * kStep);
        emb[tid] = (tid < 64) ? sinf(ang) : cosf(ang);
    }
    __syncthreads();
    {
        float a0 = 0.f, a1 = 0.f;
        for (int k = 0; k < 128; ++k) {
            float e = emb[k];
            a0 += e * W1[k * 512 + tid];
            a1 += e * W1[k * 512 + tid + 256];
        }
        float v0 = a0 + b1[tid], v1 = a1 + b1[tid + 256];
        s1[tid]       = v0 / (1.0f + expf(-v0));
        s1[tid + 256] = v1 / (1.0f + expf(-v1));
    }
    __syncthreads();
    {
        float a0 = 0.f, a1 = 0.f;
        for (int k = 0; k < 512; ++k) {
            float e = s1[k];
            a0 += e * W2[k * 512 + tid];
            a1 += e * W2[k * 512 + tid + 256];
        }
        float v0 = a0 + b2[tid], v1 = a1 + b2[tid + 256];
        s2[tid]       = v0 / (1.0f + expf(-v0));
        s2[tid + 256] = v1 / (1.0f + expf(-v1));
    }
    __syncthreads();
    {
        int c = tid & 31, seg = tid >> 5;
        float acc = 0.f;
        int k0 = seg * 64;
        for (int k = k0; k < k0 + 64; ++k)
            acc += s2[k] * Wt[k * 32 + c];
        red[tid] = acc;
        __syncthreads();
        if (tid < 32) {
            float s = 0.f;
#pragma unroll
            for (int g = 0; g < 8; ++g) s += red[g * 32 + tid];
            inj[b * 32 + tid] = s;
        }
    }
}

__global__ __launch_bounds__(256) void init_kernel(
    const int* __restrict__ batch_id, const float* __restrict__ inj,
    float4* __restrict__ out, int N)
{
    int gid = blockIdx.x * 256 + threadIdx.x;
    if (gid >= N * 8) return;
    int n = gid >> 3, q = gid & 7;
    int b = batch_id[n];
    out[gid] = ((const float4*)inj)[b * 8 + q];
}

__global__ __launch_bounds__(256) void edge_direct_kernel(
    const int* __restrict__ ei, const int* __restrict__ etype,
    const int* __restrict__ ntype, const float* __restrict__ x,
    const float* __restrict__ Wc, float* __restrict__ out, int E)
{
    __shared__ float Ws[55 * 32];
    for (int i = threadIdx.x; i < 55 * 32; i += 256) Ws[i] = Wc[i];
    __syncthreads();
    unsigned total = (unsigned)E * 32u;
    unsigned stride = gridDim.x * 256u;
    for (unsigned idx = blockIdx.x * 256u + threadIdx.x; idx < total;
         idx += stride) {
        int e = (int)(idx >> 5);
        int c = (int)(idx & 31);
        int row = ei[e];
        int col = ei[E + e];
        int T = etype[e];
        int nt = ntype[col];
        float4 xv = ((const float4*)x)[col];
        const float* wb = Ws + T * 352;
        float y = xv.x * wb[c] + xv.y * wb[32 + c] + xv.z * wb[64 + c] +
                  xv.w * wb[96 + c] + wb[(4 + nt) * 32 + c];
        atomicAdd(out + (size_t)row * 32 + c, y * 0.2f);
    }
}

extern "C" void kernel_launch(void* const* d_in, const int* in_sizes, int n_in,
                              void* d_out, int out_size, void* d_ws, size_t ws_size,
                              hipStream_t stream) {
    const float* x     = (const float*)d_in[0];   // [N,4]
    const float* t     = (const float*)d_in[1];   // [8]
    const int*   ei    = (const int*)d_in[2];     // [2,E]
    const int*   etype = (const int*)d_in[3];     // [E]
    const int*   ntype = (const int*)d_in[4];     // [N]
    const int*   batch = (const int*)d_in[5];     // [N]
    const float* Wc    = (const float*)d_in[6];   // [55,32]
    const float* W1    = (const float*)d_in[7];   // [128,512]
    const float* b1    = (const float*)d_in[8];   // [512]
    const float* W2    = (const float*)d_in[9];   // [512,512]
    const float* b2    = (const float*)d_in[10];  // [512]
    const float* Wt    = (const float*)d_in[11];  // [512,32]
    float* out = (float*)d_out;

    int E = in_sizes[3];
    int N = in_sizes[4];

    int NBC = (N + CW - 1) >> CWSH;               // coarse buckets
    int NFr = (N + WSZ - 1) >> WSH;               // consume blocks
    int NCH = (E + CH - 1) / CH;
    int NCHP = 1, LOGC = 0;
    while (NCHP < NCH) { NCHP <<= 1; ++LOGC; }
    size_t M = (size_t)NBC << LOGC;
    int nblkA = (int)((M + 4095) / 4096);

    // ws layout (4-byte units)
    float* ws     = (float*)d_ws;
    float* h1acc  = ws;                           // 4096
    float* h2acc  = ws + 4096;                    // 4096
    float* inj    = ws + 8192;                    // 256
    uint2* xh     = (uint2*)(ws + 8448);          // 2N words
    int*   counts = (int*)(ws + 8448 + 2 * (size_t)N);  // M
    int*   base   = counts + M;                   // M
    int*   bsums  = base + M;                     // 1024
    int*   bstart = bsums + 1024;                 // NBC+1
    int*   nodeSt = bstart + NBC + 1;             // N+1
    size_t recOff = 8448 + 2 * (size_t)N + 2 * M + 1024 + (NBC + 1) +
                    ((size_t)N + 1);
    recOff = (recOff + 1) & ~(size_t)1;           // 8B align
    uint2*    rec  = (uint2*)(ws + recOff);       // 2E words
    unsigned* rec2 = (unsigned*)(ws + recOff + 2 * (size_t)E);  // E words

    size_t needBytes = (recOff + 3 * (size_t)E) * 4;
    bool okay = (NBC <= NBCMAX) && (nblkA <= 1024) && (ws_size >= needBytes) &&
                (N <= NBCMAX * CW) && ((E & 3) == 0) && (M < (size_t)1 << 30);

    if (okay) {
        histW_kernel<<<NCHP + 8, 256, 0, stream>>>(
            ei, counts, x, xh, t, W1, h1acc, h2acc, inj, E, N, NBC, NCHP);
        scanA_kernel<<<nblkA + 64, 256, 0, stream>>>(
            counts, bsums, h1acc, b1, W2, h2acc, (int)M, NBC, LOGC, nblkA);
        scanB_kernel<<<1, 1024, 0, stream>>>(bsums, bstart, nblkA, NBC, E);
        scanC_kernel<<<nblkA + 8, 256, 0, stream>>>(
            counts, bsums, base, bstart, h2acc, b2, Wt, inj,
            (int)M, NBC, LOGC, nblkA);
        scatter_kernel<<<NCH, 512, 0, stream>>>(
            ei, etype, ntype, base, rec, E, NBC, LOGC);
        repack_kernel<<<NBC, 1024, 0, stream>>>(
            bstart, rec, rec2, nodeSt, NBC, N, E);
        consume_kernel<<<NFr, 512, 0, stream>>>(
            nodeSt, rec2, xh, Wc, batch, inj, out, N);
    } else {
        temb_fused_kernel<<<8, 256, 0, stream>>>(t, W1, b1, W2, b2, Wt, inj);
        init_kernel<<<(N * 8 + 255) / 256, 256, 0, stream>>>(
            batch, inj, (float4*)out, N);
        edge_direct_kernel<<<16384, 256, 0, stream>>>(
            ei, etype, ntype, x, Wc, out, E);
    }
}